// Round 1
// baseline (20959.097 us; speedup 1.0000x reference)
//
#include <hip/hip_runtime.h>
#include <math.h>

#define H 256
#define NROWS 10000
#define LTREE 8
#define TSEQ 16
#define FDIM 128
#define NE 160000

__device__ __forceinline__ float sigmoidf_(float x) { return 1.0f / (1.0f + expf(-x)); }

// Load a 64x16 f32 tile (rows m0.., cols kb..kb+15) into LDS [64][20].
// Row index clamped to Mmax-1 (guarded stores in epilogue).
__device__ __forceinline__ void load_tile(float dst[][20], const float* __restrict__ src,
                                          int m0, int Mmax, int ld, int kb, int tid) {
    int r = tid >> 2;            // 0..63
    int k4 = (tid & 3) << 2;     // 0,4,8,12
    int gr = m0 + r;
    if (gr >= Mmax) gr = Mmax - 1;
    const float4 v = *(const float4*)(src + (size_t)gr * ld + kb + k4);
    *(float4*)&dst[r][k4] = v;
}

#define DOT4(ACC, AV, BV) \
    ACC += AV.x * BV.x + AV.y * BV.y + AV.z * BV.z + AV.w * BV.w;

// ---------------------------------------------------------------------------
// GRU step: h_new = (1-z)*tanh(xn + r*ghn) + z*h_old  (fused x-proj + h-proj)
// blockIdx.z selects which of up to 4 parallel GRUs (or 2 directions).
// ---------------------------------------------------------------------------
template <int KX>
__global__ __launch_bounds__(256) void k_gru_step(
    const float* __restrict__ x0, const float* __restrict__ x1,
    const float* __restrict__ x2, const float* __restrict__ x3, int lda,
    const float* __restrict__ Wih_base, long long wih_z,
    const float* __restrict__ Whh_base, long long whh_z,
    const float* __restrict__ bih_base, const float* __restrict__ bhh_base,
    const float* __restrict__ hold_base, long long hold_z,
    float* __restrict__ out_base, long long out_z, int ldo) {
    __shared__ float As[64][20], Br[64][20], Bz[64][20], Bn[64][20];
    const int tid = threadIdx.x;
    const int tx = tid & 15, ty = tid >> 4;
    const int z = blockIdx.z;
    const int m0 = blockIdx.y * 64;
    const int cb = blockIdx.x * 64;

    const float* xs = (z == 0) ? x0 : (z == 1) ? x1 : (z == 2) ? x2 : x3;
    const float* Wih = Wih_base + (size_t)z * wih_z;
    const float* Whh = Whh_base + (size_t)z * whh_z;
    const float* bih = bih_base + z * 768;
    const float* bhh = bhh_base + z * 768;
    const float* hold = hold_base + (size_t)z * hold_z;
    float* outp = out_base + (size_t)z * out_z;

    float ar[4][4] = {{0}}, az[4][4] = {{0}}, anx[4][4] = {{0}}, anh[4][4] = {{0}};

    // ---- phase 1: x @ Wih^T (K = KX) -> ar, az, anx
    for (int kb = 0; kb < KX; kb += 16) {
        __syncthreads();
        load_tile(As, xs, m0, NROWS, lda, kb, tid);
        load_tile(Br, Wih, cb, 1 << 30, KX, kb, tid);
        load_tile(Bz, Wih, 256 + cb, 1 << 30, KX, kb, tid);
        load_tile(Bn, Wih, 512 + cb, 1 << 30, KX, kb, tid);
        __syncthreads();
#pragma unroll
        for (int kk = 0; kk < 16; kk += 4) {
            float4 av[4];
#pragma unroll
            for (int i = 0; i < 4; i++) av[i] = *(const float4*)&As[ty * 4 + i][kk];
#pragma unroll
            for (int j = 0; j < 4; j++) {
                float4 b0 = *(const float4*)&Br[tx * 4 + j][kk];
                float4 b1 = *(const float4*)&Bz[tx * 4 + j][kk];
                float4 b2 = *(const float4*)&Bn[tx * 4 + j][kk];
#pragma unroll
                for (int i = 0; i < 4; i++) {
                    DOT4(ar[i][j], av[i], b0);
                    DOT4(az[i][j], av[i], b1);
                    DOT4(anx[i][j], av[i], b2);
                }
            }
        }
    }
    // ---- phase 2: h @ Whh^T (K = 256) -> ar, az, anh
    for (int kb = 0; kb < 256; kb += 16) {
        __syncthreads();
        load_tile(As, hold, m0, NROWS, 256, kb, tid);
        load_tile(Br, Whh, cb, 1 << 30, 256, kb, tid);
        load_tile(Bz, Whh, 256 + cb, 1 << 30, 256, kb, tid);
        load_tile(Bn, Whh, 512 + cb, 1 << 30, 256, kb, tid);
        __syncthreads();
#pragma unroll
        for (int kk = 0; kk < 16; kk += 4) {
            float4 av[4];
#pragma unroll
            for (int i = 0; i < 4; i++) av[i] = *(const float4*)&As[ty * 4 + i][kk];
#pragma unroll
            for (int j = 0; j < 4; j++) {
                float4 b0 = *(const float4*)&Br[tx * 4 + j][kk];
                float4 b1 = *(const float4*)&Bz[tx * 4 + j][kk];
                float4 b2 = *(const float4*)&Bn[tx * 4 + j][kk];
#pragma unroll
                for (int i = 0; i < 4; i++) {
                    DOT4(ar[i][j], av[i], b0);
                    DOT4(az[i][j], av[i], b1);
                    DOT4(anh[i][j], av[i], b2);
                }
            }
        }
    }
    // ---- epilogue
#pragma unroll
    for (int i = 0; i < 4; i++) {
        int row = m0 + ty * 4 + i;
        if (row >= NROWS) break;
#pragma unroll
        for (int j = 0; j < 4; j++) {
            int col = cb + tx * 4 + j;
            float r = sigmoidf_(ar[i][j] + bih[col] + bhh[col]);
            float zg = sigmoidf_(az[i][j] + bih[H + col] + bhh[H + col]);
            float ng = tanhf(anx[i][j] + bih[2 * H + col] + r * (anh[i][j] + bhh[2 * H + col]));
            float hp = hold[(size_t)row * H + col];
            outp[(size_t)row * ldo + col] = (1.0f - zg) * ng + zg * hp;
        }
    }
}

// ---------------------------------------------------------------------------
// ChildSum TreeLSTM step (chain): iou gates + f gate, c in-place, h ping-pong
// ---------------------------------------------------------------------------
__global__ __launch_bounds__(256) void k_tree_step(
    const float* __restrict__ x, int lda,
    const float* __restrict__ Wioux, const float* __restrict__ Wiouh,
    const float* __restrict__ bioux, const float* __restrict__ biouh,
    const float* __restrict__ Wfx, const float* __restrict__ Wfh,
    const float* __restrict__ bfx, const float* __restrict__ bfh,
    const float* __restrict__ hold, float* __restrict__ cst,
    float* __restrict__ outp, int ldo) {
    __shared__ float As[64][20], Bi[64][20], Bo[64][20], Bu[64][20], Bf[64][20];
    const int tid = threadIdx.x;
    const int tx = tid & 15, ty = tid >> 4;
    const int m0 = blockIdx.y * 64;
    const int cb = blockIdx.x * 64;

    float ai[4][4] = {{0}}, ao[4][4] = {{0}}, au[4][4] = {{0}}, af[4][4] = {{0}};

    // phase 1: x (K=128) vs Wioux rows {cb, 256+cb, 512+cb}, Wfx row cb
    for (int kb = 0; kb < 128; kb += 16) {
        __syncthreads();
        load_tile(As, x, m0, NROWS, lda, kb, tid);
        load_tile(Bi, Wioux, cb, 1 << 30, 128, kb, tid);
        load_tile(Bo, Wioux, 256 + cb, 1 << 30, 128, kb, tid);
        load_tile(Bu, Wioux, 512 + cb, 1 << 30, 128, kb, tid);
        load_tile(Bf, Wfx, cb, 1 << 30, 128, kb, tid);
        __syncthreads();
#pragma unroll
        for (int kk = 0; kk < 16; kk += 4) {
            float4 av[4];
#pragma unroll
            for (int i = 0; i < 4; i++) av[i] = *(const float4*)&As[ty * 4 + i][kk];
#pragma unroll
            for (int j = 0; j < 4; j++) {
                float4 b0 = *(const float4*)&Bi[tx * 4 + j][kk];
                float4 b1 = *(const float4*)&Bo[tx * 4 + j][kk];
                float4 b2 = *(const float4*)&Bu[tx * 4 + j][kk];
                float4 b3 = *(const float4*)&Bf[tx * 4 + j][kk];
#pragma unroll
                for (int i = 0; i < 4; i++) {
                    DOT4(ai[i][j], av[i], b0);
                    DOT4(ao[i][j], av[i], b1);
                    DOT4(au[i][j], av[i], b2);
                    DOT4(af[i][j], av[i], b3);
                }
            }
        }
    }
    // phase 2: h (K=256) vs Wiouh / Wfh
    for (int kb = 0; kb < 256; kb += 16) {
        __syncthreads();
        load_tile(As, hold, m0, NROWS, 256, kb, tid);
        load_tile(Bi, Wiouh, cb, 1 << 30, 256, kb, tid);
        load_tile(Bo, Wiouh, 256 + cb, 1 << 30, 256, kb, tid);
        load_tile(Bu, Wiouh, 512 + cb, 1 << 30, 256, kb, tid);
        load_tile(Bf, Wfh, cb, 1 << 30, 256, kb, tid);
        __syncthreads();
#pragma unroll
        for (int kk = 0; kk < 16; kk += 4) {
            float4 av[4];
#pragma unroll
            for (int i = 0; i < 4; i++) av[i] = *(const float4*)&As[ty * 4 + i][kk];
#pragma unroll
            for (int j = 0; j < 4; j++) {
                float4 b0 = *(const float4*)&Bi[tx * 4 + j][kk];
                float4 b1 = *(const float4*)&Bo[tx * 4 + j][kk];
                float4 b2 = *(const float4*)&Bu[tx * 4 + j][kk];
                float4 b3 = *(const float4*)&Bf[tx * 4 + j][kk];
#pragma unroll
                for (int i = 0; i < 4; i++) {
                    DOT4(ai[i][j], av[i], b0);
                    DOT4(ao[i][j], av[i], b1);
                    DOT4(au[i][j], av[i], b2);
                    DOT4(af[i][j], av[i], b3);
                }
            }
        }
    }
#pragma unroll
    for (int i = 0; i < 4; i++) {
        int row = m0 + ty * 4 + i;
        if (row >= NROWS) break;
#pragma unroll
        for (int j = 0; j < 4; j++) {
            int col = cb + tx * 4 + j;
            float ig = sigmoidf_(ai[i][j] + bioux[col] + biouh[col]);
            float og = sigmoidf_(ao[i][j] + bioux[H + col] + biouh[H + col]);
            float ug = tanhf(au[i][j] + bioux[2 * H + col] + biouh[2 * H + col]);
            float fg = sigmoidf_(af[i][j] + bfx[col] + bfh[col]);
            size_t ci = (size_t)row * H + col;
            float cnew = ig * ug + fg * cst[ci];
            cst[ci] = cnew;
            outp[(size_t)row * ldo + col] = og * tanhf(cnew);
        }
    }
}

// ---------------------------------------------------------------------------
// fv += hf @ Wc[:, off_f:off_f+256]^T + hb @ Wc[:, off_b:off_b+256]^T
// ---------------------------------------------------------------------------
__global__ __launch_bounds__(256) void k_fv_acc(
    float* __restrict__ fv, const float* __restrict__ hf, const float* __restrict__ hb,
    const float* __restrict__ Wc, int off_f, int off_b) {
    __shared__ float As[64][20], Bs[64][20];
    const int tid = threadIdx.x;
    const int tx = tid & 15, ty = tid >> 4;
    const int m0 = blockIdx.y * 64;
    const int cb = blockIdx.x * 64;
    float acc[4][4] = {{0}};
    for (int ph = 0; ph < 2; ++ph) {
        const float* A = ph ? hb : hf;
        const float* B = Wc + (ph ? off_b : off_f);
        for (int kb = 0; kb < 256; kb += 16) {
            __syncthreads();
            load_tile(As, A, m0, NROWS, 256, kb, tid);
            load_tile(Bs, B, cb, 1 << 30, 2560, kb, tid);
            __syncthreads();
#pragma unroll
            for (int kk = 0; kk < 16; kk += 4) {
                float4 av[4];
#pragma unroll
                for (int i = 0; i < 4; i++) av[i] = *(const float4*)&As[ty * 4 + i][kk];
#pragma unroll
                for (int j = 0; j < 4; j++) {
                    float4 bv = *(const float4*)&Bs[tx * 4 + j][kk];
#pragma unroll
                    for (int i = 0; i < 4; i++) { DOT4(acc[i][j], av[i], bv); }
                }
            }
        }
    }
#pragma unroll
    for (int i = 0; i < 4; i++) {
        int row = m0 + ty * 4 + i;
        if (row >= NROWS) break;
#pragma unroll
        for (int j = 0; j < 4; j++) {
            int col = cb + tx * 4 + j;
            fv[(size_t)row * H + col] += acc[i][j];
        }
    }
}

// out = A @ W^T  (A [N,256], W [256,256])
__global__ __launch_bounds__(256) void k_gemm_nt(
    float* __restrict__ out, const float* __restrict__ A, const float* __restrict__ W) {
    __shared__ float As[64][20], Bs[64][20];
    const int tid = threadIdx.x;
    const int tx = tid & 15, ty = tid >> 4;
    const int m0 = blockIdx.y * 64;
    const int cb = blockIdx.x * 64;
    float acc[4][4] = {{0}};
    for (int kb = 0; kb < 256; kb += 16) {
        __syncthreads();
        load_tile(As, A, m0, NROWS, 256, kb, tid);
        load_tile(Bs, W, cb, 1 << 30, 256, kb, tid);
        __syncthreads();
#pragma unroll
        for (int kk = 0; kk < 16; kk += 4) {
            float4 av[4];
#pragma unroll
            for (int i = 0; i < 4; i++) av[i] = *(const float4*)&As[ty * 4 + i][kk];
#pragma unroll
            for (int j = 0; j < 4; j++) {
                float4 bv = *(const float4*)&Bs[tx * 4 + j][kk];
#pragma unroll
                for (int i = 0; i < 4; i++) { DOT4(acc[i][j], av[i], bv); }
            }
        }
    }
#pragma unroll
    for (int i = 0; i < 4; i++) {
        int row = m0 + ty * 4 + i;
        if (row >= NROWS) break;
#pragma unroll
        for (int j = 0; j < 4; j++) {
            out[(size_t)row * H + cb + tx * 4 + j] = acc[i][j];
        }
    }
}

// ---------------------------- small kernels -------------------------------
__global__ void k_fv_init(float* fv, const float* __restrict__ b) {
    int idx = blockIdx.x * 256 + threadIdx.x;
    if (idx < NROWS * H) fv[idx] = b[idx & (H - 1)];
}
__global__ void k_deg_init(float* deg) {
    int i = blockIdx.x * 256 + threadIdx.x;
    if (i < NROWS) deg[i] = 1.0f;  // self-loop
}
__global__ void k_deg_edges(float* deg, const int* __restrict__ dst) {
    int i = blockIdx.x * 256 + threadIdx.x;
    if (i < NE) atomicAdd(&deg[dst[i]], 1.0f);
}
__global__ void k_rsqrt(float* deg) {
    int i = blockIdx.x * 256 + threadIdx.x;
    if (i < NROWS) deg[i] = rsqrtf(deg[i]);
}
__global__ void k_agg_init(float* agg, const float* __restrict__ xw, const float* __restrict__ dinv) {
    int idx = blockIdx.x * 256 + threadIdx.x;
    if (idx < NROWS * H) {
        float d = dinv[idx >> 8];
        agg[idx] = xw[idx] * d * d;
    }
}
__global__ void k_scatter(float* __restrict__ agg, const float* __restrict__ xw,
                          const float* __restrict__ dinv, const int* __restrict__ ei) {
    int e = blockIdx.x * 4 + (threadIdx.x >> 6);
    if (e >= NE) return;
    int lane = threadIdx.x & 63;
    int s = ei[e], d = ei[NE + e];
    float w = dinv[s] * dinv[d];
    const float4 v = *(const float4*)(xw + (size_t)s * H + lane * 4);
    float* ap = agg + (size_t)d * H + lane * 4;
    atomicAdd(ap + 0, v.x * w);
    atomicAdd(ap + 1, v.y * w);
    atomicAdd(ap + 2, v.z * w);
    atomicAdd(ap + 3, v.w * w);
}
__global__ void k_bias_relu(float* __restrict__ out, const float* __restrict__ agg,
                            const float* __restrict__ b) {
    int idx = blockIdx.x * 256 + threadIdx.x;
    if (idx < NROWS * H) out[idx] = fmaxf(agg[idx] + b[idx & (H - 1)], 0.0f);
}
__global__ void k_colmax(float* __restrict__ out, const float* __restrict__ x) {
    int j = threadIdx.x;  // 256 cols
    float m = 0.0f;
    for (int r = blockIdx.x; r < NROWS; r += gridDim.x)
        m = fmaxf(m, x[(size_t)r * H + j]);
    atomicMax((int*)&out[j], __float_as_int(m));  // all values >= 0
}

// ---------------------------------------------------------------------------
extern "C" void kernel_launch(void* const* d_in, const int* in_sizes, int n_in,
                              void* d_out, int out_size, void* d_ws, size_t ws_size,
                              hipStream_t stream) {
    const float* tree = (const float*)d_in[0];
    const float* seqs[4] = {(const float*)d_in[1], (const float*)d_in[2],
                            (const float*)d_in[3], (const float*)d_in[4]};
    const int* edge = (const int*)d_in[5];
    const float* tl_Wioux = (const float*)d_in[6];
    const float* tl_bioux = (const float*)d_in[7];
    const float* tl_Wiouh = (const float*)d_in[8];
    const float* tl_biouh = (const float*)d_in[9];
    const float* tl_Wfx = (const float*)d_in[10];
    const float* tl_bfx = (const float*)d_in[11];
    const float* tl_Wfh = (const float*)d_in[12];
    const float* tl_bfh = (const float*)d_in[13];
    const float* gru_Wih = (const float*)d_in[14];
    const float* gru_Whh = (const float*)d_in[15];
    const float* gru_bih = (const float*)d_in[16];
    const float* gru_bhh = (const float*)d_in[17];
    const float* comb_Wih = (const float*)d_in[18];
    const float* comb_Whh = (const float*)d_in[19];
    const float* comb_bih = (const float*)d_in[20];
    const float* comb_bhh = (const float*)d_in[21];
    const float* connect_W = (const float*)d_in[22];
    const float* connect_b = (const float*)d_in[23];
    const float* gcn_W = (const float*)d_in[24];
    const float* gcn_b = (const float*)d_in[25];

    float* ws = (float*)d_ws;
    float* feats = ws;                              // N*5*H = 12,800,000
    float* hA = feats + (size_t)NROWS * 5 * H;      // 4*N*H = 10,240,000
    float* hB = hA + (size_t)4 * NROWS * H;         // 4*N*H
    float* cbuf = hB + (size_t)4 * NROWS * H;       // N*H
    float* fv = cbuf + (size_t)NROWS * H;           // N*H
    float* xb = fv + (size_t)NROWS * H;             // N*H
    float* xw = xb + (size_t)NROWS * H;             // N*H
    float* agg = xw + (size_t)NROWS * H;            // N*H
    float* deg = agg + (size_t)NROWS * H;           // N

    const dim3 blk(256);
    const int rowBlocks = (NROWS + 63) / 64;  // 157

    hipMemsetAsync(d_out, 0, H * sizeof(float), stream);

    // ---------------- TreeLSTM (8 steps) ----------------
    hipMemsetAsync(hA, 0, (size_t)NROWS * H * sizeof(float), stream);
    hipMemsetAsync(cbuf, 0, (size_t)NROWS * H * sizeof(float), stream);
    {
        float* hp = hA;
        float* hq = hB;
        for (int t = 0; t < LTREE; ++t) {
            float* outp = (t == LTREE - 1) ? feats : hq;
            int ldo = (t == LTREE - 1) ? 5 * H : H;
            k_tree_step<<<dim3(4, rowBlocks, 1), blk, 0, stream>>>(
                tree + t * FDIM, LTREE * FDIM, tl_Wioux, tl_Wiouh, tl_bioux, tl_biouh,
                tl_Wfx, tl_Wfh, tl_bfx, tl_bfh, hp, cbuf, outp, ldo);
            float* tmp = hp; hp = hq; hq = tmp;
        }
    }

    // ---------------- 4 GRUs (16 steps, batched in z) ----------------
    hipMemsetAsync(hA, 0, (size_t)4 * NROWS * H * sizeof(float), stream);
    {
        float* hp = hA;
        float* hq = hB;
        for (int t = 0; t < TSEQ; ++t) {
            float* ob;
            long long ozs;
            int ldo;
            if (t == TSEQ - 1) { ob = feats + H; ozs = H; ldo = 5 * H; }
            else { ob = hq; ozs = (long long)NROWS * H; ldo = H; }
            k_gru_step<128><<<dim3(4, rowBlocks, 4), blk, 0, stream>>>(
                seqs[0] + t * FDIM, seqs[1] + t * FDIM, seqs[2] + t * FDIM, seqs[3] + t * FDIM,
                TSEQ * FDIM, gru_Wih, 768LL * 128, gru_Whh, 768LL * 256, gru_bih, gru_bhh,
                hp, (long long)NROWS * H, ob, ozs, ldo);
            float* tmp = hp; hp = hq; hq = tmp;
        }
    }

    // ---------------- combine bi-GRU (5 steps) + fused connect ----------------
    hipMemsetAsync(hA, 0, (size_t)2 * NROWS * H * sizeof(float), stream);
    k_fv_init<<<(NROWS * H + 255) / 256, blk, 0, stream>>>(fv, connect_b);
    {
        float* hp = hA;
        float* hq = hB;
        for (int s = 0; s < 5; ++s) {
            k_gru_step<256><<<dim3(4, rowBlocks, 2), blk, 0, stream>>>(
                feats + s * H, feats + (4 - s) * H, feats, feats, 5 * H,
                comb_Wih, 768LL * 256, comb_Whh, 768LL * 256, comb_bih, comb_bhh,
                hp, (long long)NROWS * H, hq, (long long)NROWS * H, H);
            k_fv_acc<<<dim3(4, rowBlocks, 1), blk, 0, stream>>>(
                fv, hq, hq + (size_t)NROWS * H, connect_W, s * 2 * H, (4 - s) * 2 * H + H);
            float* tmp = hp; hp = hq; hq = tmp;
        }
    }

    // ---------------- GCN degrees ----------------
    k_deg_init<<<(NROWS + 255) / 256, blk, 0, stream>>>(deg);
    k_deg_edges<<<(NE + 255) / 256, blk, 0, stream>>>(deg, edge + NE);
    k_rsqrt<<<(NROWS + 255) / 256, blk, 0, stream>>>(deg);

    // ---------------- 4 conv applications (last two share W2,b2) ----------------
    {
        float* cur = fv;
        float* nxt = xb;
        for (int i = 0; i < 4; ++i) {
            int wi = (i < 3) ? i : 2;
            const float* W = gcn_W + (size_t)wi * H * H;
            const float* b = gcn_b + (size_t)wi * H;
            k_gemm_nt<<<dim3(4, rowBlocks, 1), blk, 0, stream>>>(xw, cur, W);
            k_agg_init<<<(NROWS * H + 255) / 256, blk, 0, stream>>>(agg, xw, deg);
            k_scatter<<<(NE + 3) / 4, blk, 0, stream>>>(agg, xw, deg, edge);
            k_bias_relu<<<(NROWS * H + 255) / 256, blk, 0, stream>>>(nxt, agg, b);
            float* tmp = cur; cur = nxt; nxt = tmp;
        }
        k_colmax<<<256, blk, 0, stream>>>((float*)d_out, cur);
    }
}

// Round 2
// 11239.696 us; speedup vs baseline: 1.8647x; 1.8647x over previous
//
#include <hip/hip_runtime.h>
#include <math.h>

#define H 256
#define NROWS 10000
#define LTREE 8
#define TSEQ 16
#define FDIM 128
#define NE 160000

typedef __attribute__((ext_vector_type(8))) short short8;
typedef __attribute__((ext_vector_type(4))) float f32x4;
typedef unsigned short u16;

__device__ __forceinline__ float sigmoidf_(float x) { return 1.0f / (1.0f + expf(-x)); }
__device__ __forceinline__ u16 f2bf(float x) {
    unsigned int u = __float_as_uint(x);
    return (u16)((u + 0x7fffu + ((u >> 16) & 1u)) >> 16);
}
__device__ __forceinline__ float bf2f(u16 s) { return __uint_as_float(((unsigned int)s) << 16); }
// load 8 consecutive f32, emit bf16 hi + lo(residual) fragments
__device__ __forceinline__ void cvt8(const float* __restrict__ p, short8& h, short8& l) {
    const float4 a = *(const float4*)p;
    const float4 b = *(const float4*)(p + 4);
    float v[8] = {a.x, a.y, a.z, a.w, b.x, b.y, b.z, b.w};
#pragma unroll
    for (int j = 0; j < 8; j++) {
        u16 hh = f2bf(v[j]);
        h[j] = (short)hh;
        l[j] = (short)f2bf(v[j] - bf2f(hh));
    }
}
__device__ __forceinline__ short8 ldf(const u16* __restrict__ p) { return *(const short8*)p; }
#define MFMA(A, B, C) C = __builtin_amdgcn_mfma_f32_16x16x32_bf16(A, B, C, 0, 0, 0)
// 3-term split product: (ah+al)*(bh+bl) ~= ah*bh + al*bh + ah*bl
#define MF3(AH, AL, BH, BL, C) do { MFMA(AH, BH, C); MFMA(AL, BH, C); MFMA(AH, BL, C); } while (0)

__global__ void k_split(const float* __restrict__ src, u16* __restrict__ hi,
                        u16* __restrict__ lo, int n) {
    int i = blockIdx.x * 256 + threadIdx.x;
    if (i < n) {
        float x = src[i];
        u16 h = f2bf(x);
        hi[i] = h;
        lo[i] = f2bf(x - bf2f(h));
    }
}

// ---------------------------------------------------------------------------
// GRU / comb-GRU step. XM=0: x from f32 global (K=128, 4 seqs by z).
//                      XM=1: x from feats hi/lo (K=256, per-z col offset).
// Block: 4 waves x 16 rows = 64 rows, 64 h-cols. 3-split MFMA, no LDS.
// ---------------------------------------------------------------------------
template <int XM>
__global__ __launch_bounds__(256) void k_rnn_step(
    const float* __restrict__ x0, const float* __restrict__ x1,
    const float* __restrict__ x2, const float* __restrict__ x3, int lda,
    const u16* __restrict__ fxh, const u16* __restrict__ fxl, int xc0, int xc1, int xld,
    const u16* __restrict__ WihH, const u16* __restrict__ WihL, long long wz,
    const u16* __restrict__ WhhH, const u16* __restrict__ WhhL, long long wzh,
    const float* __restrict__ bihB, const float* __restrict__ bhhB,
    const u16* __restrict__ hpH, const u16* __restrict__ hpL, long long hz,
    u16* __restrict__ oH, u16* __restrict__ oL, long long ozs, int oldv, int ocoff) {
    constexpr int KX = (XM == 0) ? 128 : 256;
    const int tid = threadIdx.x, lane = tid & 63, w = tid >> 6;
    const int lx = lane & 15, kl = (lane >> 4) * 8;
    const int z = blockIdx.z, cb = blockIdx.x * 64, m0 = blockIdx.y * 64;
    int arow = m0 + 16 * w + lx;
    if (arow > NROWS - 1) arow = NROWS - 1;

    const u16* WihHz = WihH + (size_t)z * wz;
    const u16* WihLz = WihL + (size_t)z * wz;
    const u16* WhhHz = WhhH + (size_t)z * wzh;
    const u16* WhhLz = WhhL + (size_t)z * wzh;
    const float* bih = bihB + z * 768;
    const float* bhh = bhhB + z * 768;
    const u16* hph = hpH + (size_t)z * hz;
    const u16* hpl = hpL + (size_t)z * hz;

    const f32x4 zf = {0.f, 0.f, 0.f, 0.f};
    f32x4 aR[4] = {zf, zf, zf, zf}, aZ[4] = {zf, zf, zf, zf};
    f32x4 aNX[4] = {zf, zf, zf, zf}, aNH[4] = {zf, zf, zf, zf};

    // ---- phase X: x @ Wih^T
    const float* xs = (XM == 0) ? ((z == 0) ? x0 : (z == 1) ? x1 : (z == 2) ? x2 : x3) : (const float*)0;
    const int xcoff = (z == 0) ? xc0 : xc1;
    for (int kb = 0; kb < KX; kb += 32) {
        short8 axh, axl;
        if constexpr (XM == 0) {
            cvt8(xs + (size_t)arow * lda + kb + kl, axh, axl);
        } else {
            size_t xi = (size_t)arow * xld + xcoff + kb + kl;
            axh = ldf(fxh + xi);
            axl = ldf(fxl + xi);
        }
#pragma unroll
        for (int n = 0; n < 4; n++) {
            size_t bi = (size_t)(cb + n * 16 + lx) * KX + kb + kl;
            short8 brh = ldf(WihHz + bi), brl = ldf(WihLz + bi);
            short8 bzh = ldf(WihHz + bi + (size_t)256 * KX), bzl = ldf(WihLz + bi + (size_t)256 * KX);
            short8 bnh = ldf(WihHz + bi + (size_t)512 * KX), bnl = ldf(WihLz + bi + (size_t)512 * KX);
            MF3(axh, axl, brh, brl, aR[n]);
            MF3(axh, axl, bzh, bzl, aZ[n]);
            MF3(axh, axl, bnh, bnl, aNX[n]);
        }
    }
    // ---- phase H: h @ Whh^T (K=256)
    for (int kb = 0; kb < 256; kb += 32) {
        size_t xi = (size_t)arow * H + kb + kl;
        short8 axh = ldf(hph + xi), axl = ldf(hpl + xi);
#pragma unroll
        for (int n = 0; n < 4; n++) {
            size_t bi = (size_t)(cb + n * 16 + lx) * 256 + kb + kl;
            short8 brh = ldf(WhhHz + bi), brl = ldf(WhhLz + bi);
            short8 bzh = ldf(WhhHz + bi + 65536), bzl = ldf(WhhLz + bi + 65536);
            short8 bnh = ldf(WhhHz + bi + 131072), bnl = ldf(WhhLz + bi + 131072);
            MF3(axh, axl, brh, brl, aR[n]);
            MF3(axh, axl, bzh, bzl, aZ[n]);
            MF3(axh, axl, bnh, bnl, aNH[n]);
        }
    }
    // ---- epilogue: gates + state update; write h as bf16 hi/lo
#pragma unroll
    for (int n = 0; n < 4; n++) {
        int col = cb + n * 16 + lx;
        float b_r = bih[col] + bhh[col];
        float b_z = bih[256 + col] + bhh[256 + col];
        float bx_n = bih[512 + col], bh_n = bhh[512 + col];
#pragma unroll
        for (int r = 0; r < 4; r++) {
            int row = m0 + 16 * w + (lane >> 4) * 4 + r;
            if (row < NROWS) {
                float rg = sigmoidf_(aR[n][r] + b_r);
                float zg = sigmoidf_(aZ[n][r] + b_z);
                float ng = tanhf(aNX[n][r] + bx_n + rg * (aNH[n][r] + bh_n));
                size_t hidx = (size_t)row * H + col;
                float hold = bf2f(hph[hidx]) + bf2f(hpl[hidx]);
                float hnew = (1.0f - zg) * ng + zg * hold;
                size_t oi = (size_t)z * ozs + (size_t)row * oldv + ocoff + col;
                u16 hh = f2bf(hnew);
                oH[oi] = hh;
                oL[oi] = f2bf(hnew - bf2f(hh));
            }
        }
    }
}

// ---------------------------------------------------------------------------
// ChildSum TreeLSTM step (chain). i,o,u,f gates, c in f32 (in-place).
// ---------------------------------------------------------------------------
__global__ __launch_bounds__(256) void k_tree_step_mf(
    const float* __restrict__ x, int lda,
    const u16* __restrict__ WxH, const u16* __restrict__ WxL,
    const u16* __restrict__ WhH, const u16* __restrict__ WhL,
    const u16* __restrict__ WfxH, const u16* __restrict__ WfxL,
    const u16* __restrict__ WfhH, const u16* __restrict__ WfhL,
    const float* __restrict__ bioux, const float* __restrict__ biouh,
    const float* __restrict__ bfx, const float* __restrict__ bfh,
    const u16* __restrict__ hpH, const u16* __restrict__ hpL,
    float* __restrict__ cst, u16* __restrict__ oH, u16* __restrict__ oL, int oldv) {
    const int tid = threadIdx.x, lane = tid & 63, w = tid >> 6;
    const int lx = lane & 15, kl = (lane >> 4) * 8;
    const int cb = blockIdx.x * 64, m0 = blockIdx.y * 64;
    int arow = m0 + 16 * w + lx;
    if (arow > NROWS - 1) arow = NROWS - 1;

    const f32x4 zf = {0.f, 0.f, 0.f, 0.f};
    f32x4 aI[4] = {zf, zf, zf, zf}, aO[4] = {zf, zf, zf, zf};
    f32x4 aU[4] = {zf, zf, zf, zf}, aF[4] = {zf, zf, zf, zf};

    for (int kb = 0; kb < 128; kb += 32) {  // x phase, K=128
        short8 axh, axl;
        cvt8(x + (size_t)arow * lda + kb + kl, axh, axl);
#pragma unroll
        for (int n = 0; n < 4; n++) {
            size_t bi = (size_t)(cb + n * 16 + lx) * 128 + kb + kl;
            short8 bih_ = ldf(WxH + bi), bil_ = ldf(WxL + bi);
            short8 boh = ldf(WxH + bi + 32768), bol = ldf(WxL + bi + 32768);
            short8 buh = ldf(WxH + bi + 65536), bul = ldf(WxL + bi + 65536);
            short8 bfh_ = ldf(WfxH + bi), bfl_ = ldf(WfxL + bi);
            MF3(axh, axl, bih_, bil_, aI[n]);
            MF3(axh, axl, boh, bol, aO[n]);
            MF3(axh, axl, buh, bul, aU[n]);
            MF3(axh, axl, bfh_, bfl_, aF[n]);
        }
    }
    for (int kb = 0; kb < 256; kb += 32) {  // h phase, K=256
        size_t xi = (size_t)arow * H + kb + kl;
        short8 axh = ldf(hpH + xi), axl = ldf(hpL + xi);
#pragma unroll
        for (int n = 0; n < 4; n++) {
            size_t bi = (size_t)(cb + n * 16 + lx) * 256 + kb + kl;
            short8 bih_ = ldf(WhH + bi), bil_ = ldf(WhL + bi);
            short8 boh = ldf(WhH + bi + 65536), bol = ldf(WhL + bi + 65536);
            short8 buh = ldf(WhH + bi + 131072), bul = ldf(WhL + bi + 131072);
            short8 bfh_ = ldf(WfhH + bi), bfl_ = ldf(WfhL + bi);
            MF3(axh, axl, bih_, bil_, aI[n]);
            MF3(axh, axl, boh, bol, aO[n]);
            MF3(axh, axl, buh, bul, aU[n]);
            MF3(axh, axl, bfh_, bfl_, aF[n]);
        }
    }
#pragma unroll
    for (int n = 0; n < 4; n++) {
        int col = cb + n * 16 + lx;
        float b_i = bioux[col] + biouh[col];
        float b_o = bioux[256 + col] + biouh[256 + col];
        float b_u = bioux[512 + col] + biouh[512 + col];
        float b_f = bfx[col] + bfh[col];
#pragma unroll
        for (int r = 0; r < 4; r++) {
            int row = m0 + 16 * w + (lane >> 4) * 4 + r;
            if (row < NROWS) {
                float ig = sigmoidf_(aI[n][r] + b_i);
                float og = sigmoidf_(aO[n][r] + b_o);
                float ug = tanhf(aU[n][r] + b_u);
                float fg = sigmoidf_(aF[n][r] + b_f);
                size_t ci = (size_t)row * H + col;
                float cnew = ig * ug + fg * cst[ci];
                cst[ci] = cnew;
                float hnew = og * tanhf(cnew);
                size_t oi = (size_t)row * oldv + col;
                u16 hh = f2bf(hnew);
                oH[oi] = hh;
                oL[oi] = f2bf(hnew - bf2f(hh));
            }
        }
    }
}

// fv += hf @ Wc[:,off_f:+256]^T + hb @ Wc[:,off_b:+256]^T  (Wc ld = 2560)
__global__ __launch_bounds__(256) void k_fv_acc_mf(
    float* __restrict__ fv, const u16* __restrict__ hqH, const u16* __restrict__ hqL,
    const u16* __restrict__ WcH, const u16* __restrict__ WcL, int off_f, int off_b) {
    const int tid = threadIdx.x, lane = tid & 63, w = tid >> 6;
    const int lx = lane & 15, kl = (lane >> 4) * 8;
    const int cb = blockIdx.x * 64, m0 = blockIdx.y * 64;
    int arow = m0 + 16 * w + lx;
    if (arow > NROWS - 1) arow = NROWS - 1;
    const f32x4 zf = {0.f, 0.f, 0.f, 0.f};
    f32x4 acc[4] = {zf, zf, zf, zf};
    for (int ph = 0; ph < 2; ph++) {
        const u16* ah = hqH + (size_t)ph * NROWS * H;
        const u16* al = hqL + (size_t)ph * NROWS * H;
        const int off = ph ? off_b : off_f;
        for (int kb = 0; kb < 256; kb += 32) {
            size_t xi = (size_t)arow * H + kb + kl;
            short8 axh = ldf(ah + xi), axl = ldf(al + xi);
#pragma unroll
            for (int n = 0; n < 4; n++) {
                size_t bi = (size_t)(cb + n * 16 + lx) * 2560 + off + kb + kl;
                short8 bh = ldf(WcH + bi), bl = ldf(WcL + bi);
                MF3(axh, axl, bh, bl, acc[n]);
            }
        }
    }
#pragma unroll
    for (int n = 0; n < 4; n++) {
        int col = cb + n * 16 + lx;
#pragma unroll
        for (int r = 0; r < 4; r++) {
            int row = m0 + 16 * w + (lane >> 4) * 4 + r;
            if (row < NROWS) fv[(size_t)row * H + col] += acc[n][r];
        }
    }
}

// out = A(f32) @ W^T   (A [N,256] converted in-kernel, W [256,256] hi/lo)
__global__ __launch_bounds__(256) void k_gcn_gemm(
    float* __restrict__ out, const float* __restrict__ A,
    const u16* __restrict__ WH, const u16* __restrict__ WL) {
    const int tid = threadIdx.x, lane = tid & 63, w = tid >> 6;
    const int lx = lane & 15, kl = (lane >> 4) * 8;
    const int cb = blockIdx.x * 64, m0 = blockIdx.y * 64;
    int arow = m0 + 16 * w + lx;
    if (arow > NROWS - 1) arow = NROWS - 1;
    const f32x4 zf = {0.f, 0.f, 0.f, 0.f};
    f32x4 acc[4] = {zf, zf, zf, zf};
    for (int kb = 0; kb < 256; kb += 32) {
        short8 axh, axl;
        cvt8(A + (size_t)arow * H + kb + kl, axh, axl);
#pragma unroll
        for (int n = 0; n < 4; n++) {
            size_t bi = (size_t)(cb + n * 16 + lx) * 256 + kb + kl;
            short8 bh = ldf(WH + bi), bl = ldf(WL + bi);
            MF3(axh, axl, bh, bl, acc[n]);
        }
    }
#pragma unroll
    for (int n = 0; n < 4; n++) {
        int col = cb + n * 16 + lx;
#pragma unroll
        for (int r = 0; r < 4; r++) {
            int row = m0 + 16 * w + (lane >> 4) * 4 + r;
            if (row < NROWS) out[(size_t)row * H + col] = acc[n][r];
        }
    }
}

// ---------------------------- small kernels -------------------------------
__global__ void k_fv_init(float* fv, const float* __restrict__ b) {
    int idx = blockIdx.x * 256 + threadIdx.x;
    if (idx < NROWS * H) fv[idx] = b[idx & (H - 1)];
}
__global__ void k_deg_init(float* deg) {
    int i = blockIdx.x * 256 + threadIdx.x;
    if (i < NROWS) deg[i] = 1.0f;
}
__global__ void k_deg_edges(float* deg, const int* __restrict__ dst) {
    int i = blockIdx.x * 256 + threadIdx.x;
    if (i < NE) atomicAdd(&deg[dst[i]], 1.0f);
}
__global__ void k_rsqrt(float* deg) {
    int i = blockIdx.x * 256 + threadIdx.x;
    if (i < NROWS) deg[i] = rsqrtf(deg[i]);
}
__global__ void k_agg_init(float* agg, const float* __restrict__ xw, const float* __restrict__ dinv) {
    int idx = blockIdx.x * 256 + threadIdx.x;
    if (idx < NROWS * H) {
        float d = dinv[idx >> 8];
        agg[idx] = xw[idx] * d * d;
    }
}
__global__ void k_scatter(float* __restrict__ agg, const float* __restrict__ xw,
                          const float* __restrict__ dinv, const int* __restrict__ ei) {
    int e = blockIdx.x * 4 + (threadIdx.x >> 6);
    if (e >= NE) return;
    int lane = threadIdx.x & 63;
    int s = ei[e], d = ei[NE + e];
    float wgt = dinv[s] * dinv[d];
    const float4 v = *(const float4*)(xw + (size_t)s * H + lane * 4);
    float* ap = agg + (size_t)d * H + lane * 4;
    atomicAdd(ap + 0, v.x * wgt);
    atomicAdd(ap + 1, v.y * wgt);
    atomicAdd(ap + 2, v.z * wgt);
    atomicAdd(ap + 3, v.w * wgt);
}
__global__ void k_bias_relu(float* __restrict__ out, const float* __restrict__ agg,
                            const float* __restrict__ b) {
    int idx = blockIdx.x * 256 + threadIdx.x;
    if (idx < NROWS * H) out[idx] = fmaxf(agg[idx] + b[idx & (H - 1)], 0.0f);
}
__global__ void k_colmax(float* __restrict__ out, const float* __restrict__ x) {
    int j = threadIdx.x;
    float m = 0.0f;
    for (int r = blockIdx.x; r < NROWS; r += gridDim.x)
        m = fmaxf(m, x[(size_t)r * H + j]);
    atomicMax((int*)&out[j], __float_as_int(m));
}

// ---------------------------------------------------------------------------
extern "C" void kernel_launch(void* const* d_in, const int* in_sizes, int n_in,
                              void* d_out, int out_size, void* d_ws, size_t ws_size,
                              hipStream_t stream) {
    const float* tree = (const float*)d_in[0];
    const float* s2 = (const float*)d_in[1];
    const float* s3 = (const float*)d_in[2];
    const float* s4 = (const float*)d_in[3];
    const float* s5 = (const float*)d_in[4];
    const int* edge = (const int*)d_in[5];
    const float* tl_Wioux = (const float*)d_in[6];
    const float* tl_bioux = (const float*)d_in[7];
    const float* tl_Wiouh = (const float*)d_in[8];
    const float* tl_biouh = (const float*)d_in[9];
    const float* tl_Wfx = (const float*)d_in[10];
    const float* tl_bfx = (const float*)d_in[11];
    const float* tl_Wfh = (const float*)d_in[12];
    const float* tl_bfh = (const float*)d_in[13];
    const float* gru_Wih = (const float*)d_in[14];
    const float* gru_Whh = (const float*)d_in[15];
    const float* gru_bih = (const float*)d_in[16];
    const float* gru_bhh = (const float*)d_in[17];
    const float* comb_Wih = (const float*)d_in[18];
    const float* comb_Whh = (const float*)d_in[19];
    const float* comb_bih = (const float*)d_in[20];
    const float* comb_bhh = (const float*)d_in[21];
    const float* connect_W = (const float*)d_in[22];
    const float* connect_b = (const float*)d_in[23];
    const float* gcn_W = (const float*)d_in[24];
    const float* gcn_b = (const float*)d_in[25];

    char* base = (char*)d_ws;
    size_t off = 0;
    auto aus = [&](size_t n) { u16* p = (u16*)(base + off); off += n * sizeof(u16); return p; };
    u16* txH = aus(98304);   u16* txL = aus(98304);      // tl_Wioux
    u16* thH = aus(196608);  u16* thL = aus(196608);     // tl_Wiouh
    u16* tfxH = aus(32768);  u16* tfxL = aus(32768);     // tl_Wfx
    u16* tfhH = aus(65536);  u16* tfhL = aus(65536);     // tl_Wfh
    u16* gWihH = aus(393216); u16* gWihL = aus(393216);  // gru_Wih [4][768][128]
    u16* gWhhH = aus(786432); u16* gWhhL = aus(786432);  // gru_Whh [4][768][256]
    u16* cWihH = aus(393216); u16* cWihL = aus(393216);  // comb_Wih [2][768][256]
    u16* cWhhH = aus(393216); u16* cWhhL = aus(393216);  // comb_Whh
    u16* cnH = aus(655360);  u16* cnL = aus(655360);     // connect_W [256][2560]
    u16* gcH = aus(196608);  u16* gcL = aus(196608);     // gcn_W [3][256][256]
    u16* featsH = aus((size_t)NROWS * 5 * H);
    u16* featsL = aus((size_t)NROWS * 5 * H);
    u16* hAH = aus((size_t)4 * NROWS * H);
    u16* hAL = aus((size_t)4 * NROWS * H);
    u16* hBH = aus((size_t)4 * NROWS * H);
    u16* hBL = aus((size_t)4 * NROWS * H);
    float* cbuf = (float*)(base + off); off += (size_t)NROWS * H * 4;
    float* fv = (float*)(base + off);   off += (size_t)NROWS * H * 4;
    // GCN scratch aliased onto dead RNN ping-pong buffers (each 20.48 MB)
    float* xw = (float*)hAH;
    float* xb = (float*)hAL;
    float* agg = (float*)hBH;
    float* deg = (float*)hBL;

    const dim3 blk(256);
    const int MB = (NROWS + 63) / 64;  // 157

    hipMemsetAsync(d_out, 0, H * sizeof(float), stream);

    // -------- split weights to bf16 hi/lo --------
    auto SP = [&](const float* s, u16* h, u16* l, int n) {
        k_split<<<(n + 255) / 256, blk, 0, stream>>>(s, h, l, n);
    };
    SP(tl_Wioux, txH, txL, 98304);
    SP(tl_Wiouh, thH, thL, 196608);
    SP(tl_Wfx, tfxH, tfxL, 32768);
    SP(tl_Wfh, tfhH, tfhL, 65536);
    SP(gru_Wih, gWihH, gWihL, 393216);
    SP(gru_Whh, gWhhH, gWhhL, 786432);
    SP(comb_Wih, cWihH, cWihL, 393216);
    SP(comb_Whh, cWhhH, cWhhL, 393216);
    SP(connect_W, cnH, cnL, 655360);
    SP(gcn_W, gcH, gcL, 196608);

    // -------- TreeLSTM (8 steps) --------
    hipMemsetAsync(hAH, 0, (size_t)NROWS * H * 2, stream);
    hipMemsetAsync(hAL, 0, (size_t)NROWS * H * 2, stream);
    hipMemsetAsync(cbuf, 0, (size_t)NROWS * H * 4, stream);
    {
        u16 *pH = hAH, *pL = hAL, *qH = hBH, *qL = hBL;
        for (int t = 0; t < LTREE; ++t) {
            bool last = (t == LTREE - 1);
            k_tree_step_mf<<<dim3(4, MB, 1), blk, 0, stream>>>(
                tree + t * FDIM, LTREE * FDIM, txH, txL, thH, thL, tfxH, tfxL, tfhH, tfhL,
                tl_bioux, tl_biouh, tl_bfx, tl_bfh, pH, pL, cbuf,
                last ? featsH : qH, last ? featsL : qL, last ? 5 * H : H);
            u16* t1 = pH; pH = qH; qH = t1;
            u16* t2 = pL; pL = qL; qL = t2;
        }
    }

    // -------- 4 GRUs (16 steps, z=4) --------
    hipMemsetAsync(hAH, 0, (size_t)4 * NROWS * H * 2, stream);
    hipMemsetAsync(hAL, 0, (size_t)4 * NROWS * H * 2, stream);
    {
        u16 *pH = hAH, *pL = hAL, *qH = hBH, *qL = hBL;
        for (int t = 0; t < TSEQ; ++t) {
            bool last = (t == TSEQ - 1);
            k_rnn_step<0><<<dim3(4, MB, 4), blk, 0, stream>>>(
                s2 + t * FDIM, s3 + t * FDIM, s4 + t * FDIM, s5 + t * FDIM, TSEQ * FDIM,
                (const u16*)0, (const u16*)0, 0, 0, 0,
                gWihH, gWihL, 98304LL, gWhhH, gWhhL, 196608LL, gru_bih, gru_bhh,
                pH, pL, (long long)NROWS * H,
                last ? featsH + H : qH, last ? featsL + H : qL,
                last ? (long long)H : (long long)NROWS * H, last ? 5 * H : H, 0);
            u16* t1 = pH; pH = qH; qH = t1;
            u16* t2 = pL; pL = qL; qL = t2;
        }
    }

    // -------- combine bi-GRU (5 steps, z=2) + fused connect --------
    hipMemsetAsync(hAH, 0, (size_t)2 * NROWS * H * 2, stream);
    hipMemsetAsync(hAL, 0, (size_t)2 * NROWS * H * 2, stream);
    k_fv_init<<<(NROWS * H + 255) / 256, blk, 0, stream>>>(fv, connect_b);
    {
        u16 *pH = hAH, *pL = hAL, *qH = hBH, *qL = hBL;
        for (int s = 0; s < 5; ++s) {
            k_rnn_step<1><<<dim3(4, MB, 2), blk, 0, stream>>>(
                (const float*)0, (const float*)0, (const float*)0, (const float*)0, 0,
                featsH, featsL, s * H, (4 - s) * H, 5 * H,
                cWihH, cWihL, 196608LL, cWhhH, cWhhL, 196608LL, comb_bih, comb_bhh,
                pH, pL, (long long)NROWS * H,
                qH, qL, (long long)NROWS * H, H, 0);
            k_fv_acc_mf<<<dim3(4, MB, 1), blk, 0, stream>>>(
                fv, qH, qL, cnH, cnL, s * 512, (4 - s) * 512 + 256);
            u16* t1 = pH; pH = qH; qH = t1;
            u16* t2 = pL; pL = qL; qL = t2;
        }
    }

    // -------- GCN degrees --------
    k_deg_init<<<(NROWS + 255) / 256, blk, 0, stream>>>(deg);
    k_deg_edges<<<(NE + 255) / 256, blk, 0, stream>>>(deg, edge + NE);
    k_rsqrt<<<(NROWS + 255) / 256, blk, 0, stream>>>(deg);

    // -------- 4 conv applications (last two share W2,b2) --------
    {
        float* cur = fv;
        float* nxt = xb;
        for (int i = 0; i < 4; ++i) {
            int wi = (i < 3) ? i : 2;
            k_gcn_gemm<<<dim3(4, MB, 1), blk, 0, stream>>>(xw, cur, gcH + wi * 65536, gcL + wi * 65536);
            k_agg_init<<<(NROWS * H + 255) / 256, blk, 0, stream>>>(agg, xw, deg);
            k_scatter<<<(NE + 3) / 4, blk, 0, stream>>>(agg, xw, deg, edge);
            k_bias_relu<<<(NROWS * H + 255) / 256, blk, 0, stream>>>(nxt, agg, gcn_b + wi * H);
            float* tmp = cur; cur = nxt; nxt = tmp;
        }
        k_colmax<<<256, blk, 0, stream>>>((float*)d_out, cur);
    }
}

// Round 3
// 6231.414 us; speedup vs baseline: 3.3635x; 1.8037x over previous
//
#include <hip/hip_runtime.h>
#include <math.h>

#define H 256
#define NROWS 10000
#define LTREE 8
#define TSEQ 16
#define FDIM 128
#define NE 160000

typedef __attribute__((ext_vector_type(8))) short short8;
typedef __attribute__((ext_vector_type(4))) float f32x4;
typedef unsigned short u16;

__device__ __forceinline__ float sigmoidf_(float x) { return 1.0f / (1.0f + expf(-x)); }
__device__ __forceinline__ u16 f2bf(float x) {
    unsigned int u = __float_as_uint(x);
    return (u16)((u + 0x7fffu + ((u >> 16) & 1u)) >> 16);
}
__device__ __forceinline__ float bf2f(u16 s) { return __uint_as_float(((unsigned int)s) << 16); }
__device__ __forceinline__ short8 ldf(const u16* __restrict__ p) { return *(const short8*)(p); }
#define MFMA(A, B, C) C = __builtin_amdgcn_mfma_f32_16x16x32_bf16(A, B, C, 0, 0, 0)
#define MF3(AH, AL, BH, BL, C) do { MFMA(AH, BH, C); MFMA(AL, BH, C); MFMA(AH, BL, C); } while (0)

// -------------------- split helpers --------------------
__global__ void k_split(const float* __restrict__ src, u16* __restrict__ hi,
                        u16* __restrict__ lo, int n) {
    int i = blockIdx.x * 256 + threadIdx.x;
    if (i < n) {
        float x = src[i];
        u16 h = f2bf(x);
        hi[i] = h;
        lo[i] = f2bf(x - bf2f(h));
    }
}
// strided slice [NROWS x 128] from src with leading dim ld
__global__ void k_split_str(const float* __restrict__ src, int ld,
                            u16* __restrict__ oh, u16* __restrict__ ol) {
    int idx = blockIdx.x * 256 + threadIdx.x;
    if (idx < NROWS * FDIM) {
        int row = idx >> 7, col = idx & 127;
        float v = src[(size_t)row * ld + col];
        u16 h = f2bf(v);
        oh[idx] = h;
        ol[idx] = f2bf(v - bf2f(h));
    }
}
// timestep t of the 4 sequences -> [4][NROWS][128]
__global__ void k_split_seq(const float* __restrict__ s2, const float* __restrict__ s3,
                            const float* __restrict__ s4, const float* __restrict__ s5,
                            int t, u16* __restrict__ oh, u16* __restrict__ ol) {
    int idx = blockIdx.x * 256 + threadIdx.x;
    int z = blockIdx.z;
    if (idx < NROWS * FDIM) {
        const float* s = (z == 0) ? s2 : (z == 1) ? s3 : (z == 2) ? s4 : s5;
        int row = idx >> 7, col = idx & 127;
        float v = s[(size_t)row * (TSEQ * FDIM) + t * FDIM + col];
        u16 h = f2bf(v);
        size_t oi = (size_t)z * NROWS * FDIM + idx;
        oh[oi] = h;
        ol[oi] = f2bf(v - bf2f(h));
    }
}

// ---------------------------------------------------------------------------
// GRU step, register-blocked: wave = 64 rows (4 rf) x 16 cols per gate class.
// Block = 4 waves stacked on rows (256 rows). grid(16, 40, z).
// x pre-split to bf16 hi/lo. KX = 128 (seq GRUs) or 256 (comb).
// ---------------------------------------------------------------------------
template <int KX>
__global__ __launch_bounds__(256) void k_rnn_step(
    const u16* __restrict__ fxh, const u16* __restrict__ fxl,
    long long xzs, int xld, int xc0, int xc1,
    const u16* __restrict__ WihH, const u16* __restrict__ WihL, long long wz,
    const u16* __restrict__ WhhH, const u16* __restrict__ WhhL, long long wzh,
    const float* __restrict__ bihB, const float* __restrict__ bhhB,
    const u16* __restrict__ hpH, const u16* __restrict__ hpL, long long hz,
    u16* __restrict__ oH, u16* __restrict__ oL, long long ozs, int oldv, int ocoff) {
    const int tid = threadIdx.x, lane = tid & 63, w = tid >> 6;
    const int lx = lane & 15, kl = (lane >> 4) * 8;
    const int z = blockIdx.z;
    const int cb = blockIdx.x * 16;
    const int m0 = blockIdx.y * 256 + w * 64;
    int arow[4];
#pragma unroll
    for (int rf = 0; rf < 4; rf++) {
        int r = m0 + rf * 16 + lx;
        arow[rf] = (r < NROWS) ? r : NROWS - 1;
    }
    const u16* xh = fxh + (size_t)z * xzs;
    const u16* xl = fxl + (size_t)z * xzs;
    const int xco = (z == 1) ? xc1 : xc0;
    const u16* WihHz = WihH + (size_t)z * wz;
    const u16* WihLz = WihL + (size_t)z * wz;
    const u16* WhhHz = WhhH + (size_t)z * wzh;
    const u16* WhhLz = WhhL + (size_t)z * wzh;
    const float* bih = bihB + z * 768;
    const float* bhh = bhhB + z * 768;
    const u16* hph = hpH + (size_t)z * hz;
    const u16* hpl = hpL + (size_t)z * hz;

    const f32x4 zf = {0.f, 0.f, 0.f, 0.f};
    f32x4 aR[4] = {zf, zf, zf, zf}, aZ[4] = {zf, zf, zf, zf};
    f32x4 aNX[4] = {zf, zf, zf, zf}, aNH[4] = {zf, zf, zf, zf};

    // ---- phase X: x @ Wih^T (classes r, z, nx)
    for (int kb = 0; kb < KX; kb += 32) {
        short8 axh[4], axl[4];
#pragma unroll
        for (int rf = 0; rf < 4; rf++) {
            size_t xi = (size_t)arow[rf] * xld + xco + kb + kl;
            axh[rf] = ldf(xh + xi);
            axl[rf] = ldf(xl + xi);
        }
        size_t bi = (size_t)(cb + lx) * KX + kb + kl;
        {
            short8 bh = ldf(WihHz + bi), bl = ldf(WihLz + bi);
#pragma unroll
            for (int rf = 0; rf < 4; rf++) MF3(axh[rf], axl[rf], bh, bl, aR[rf]);
        }
        {
            short8 bh = ldf(WihHz + bi + (size_t)256 * KX), bl = ldf(WihLz + bi + (size_t)256 * KX);
#pragma unroll
            for (int rf = 0; rf < 4; rf++) MF3(axh[rf], axl[rf], bh, bl, aZ[rf]);
        }
        {
            short8 bh = ldf(WihHz + bi + (size_t)512 * KX), bl = ldf(WihLz + bi + (size_t)512 * KX);
#pragma unroll
            for (int rf = 0; rf < 4; rf++) MF3(axh[rf], axl[rf], bh, bl, aNX[rf]);
        }
    }
    // ---- phase H: h @ Whh^T (classes r, z, nh)
    for (int kb = 0; kb < 256; kb += 32) {
        short8 axh[4], axl[4];
#pragma unroll
        for (int rf = 0; rf < 4; rf++) {
            size_t xi = (size_t)arow[rf] * H + kb + kl;
            axh[rf] = ldf(hph + xi);
            axl[rf] = ldf(hpl + xi);
        }
        size_t bi = (size_t)(cb + lx) * 256 + kb + kl;
        {
            short8 bh = ldf(WhhHz + bi), bl = ldf(WhhLz + bi);
#pragma unroll
            for (int rf = 0; rf < 4; rf++) MF3(axh[rf], axl[rf], bh, bl, aR[rf]);
        }
        {
            short8 bh = ldf(WhhHz + bi + 65536), bl = ldf(WhhLz + bi + 65536);
#pragma unroll
            for (int rf = 0; rf < 4; rf++) MF3(axh[rf], axl[rf], bh, bl, aZ[rf]);
        }
        {
            short8 bh = ldf(WhhHz + bi + 131072), bl = ldf(WhhLz + bi + 131072);
#pragma unroll
            for (int rf = 0; rf < 4; rf++) MF3(axh[rf], axl[rf], bh, bl, aNH[rf]);
        }
    }
    // ---- epilogue
    const int col = cb + lx;
    const float b_r = bih[col] + bhh[col];
    const float b_z = bih[256 + col] + bhh[256 + col];
    const float bx_n = bih[512 + col], bh_n = bhh[512 + col];
#pragma unroll
    for (int rf = 0; rf < 4; rf++) {
#pragma unroll
        for (int rr = 0; rr < 4; rr++) {
            int row = m0 + rf * 16 + (lane >> 4) * 4 + rr;
            if (row < NROWS) {
                float rg = sigmoidf_(aR[rf][rr] + b_r);
                float zg = sigmoidf_(aZ[rf][rr] + b_z);
                float ng = tanhf(aNX[rf][rr] + bx_n + rg * (aNH[rf][rr] + bh_n));
                size_t hidx = (size_t)row * H + col;
                float hold = bf2f(hph[hidx]) + bf2f(hpl[hidx]);
                float hnew = (1.0f - zg) * ng + zg * hold;
                size_t oi = (size_t)z * ozs + (size_t)row * oldv + ocoff + col;
                u16 hh = f2bf(hnew);
                oH[oi] = hh;
                oL[oi] = f2bf(hnew - bf2f(hh));
            }
        }
    }
}

// ---------------------------------------------------------------------------
// TreeLSTM step (chain), same geometry. Classes i,o,u + f. c in f32, in place.
// ---------------------------------------------------------------------------
__global__ __launch_bounds__(256) void k_tree_step_mf(
    const u16* __restrict__ txh, const u16* __restrict__ txl,
    const u16* __restrict__ WxH, const u16* __restrict__ WxL,
    const u16* __restrict__ WhH, const u16* __restrict__ WhL,
    const u16* __restrict__ WfxH, const u16* __restrict__ WfxL,
    const u16* __restrict__ WfhH, const u16* __restrict__ WfhL,
    const float* __restrict__ bioux, const float* __restrict__ biouh,
    const float* __restrict__ bfx, const float* __restrict__ bfh,
    const u16* __restrict__ hpH, const u16* __restrict__ hpL,
    float* __restrict__ cst, u16* __restrict__ oH, u16* __restrict__ oL, int oldv) {
    const int tid = threadIdx.x, lane = tid & 63, w = tid >> 6;
    const int lx = lane & 15, kl = (lane >> 4) * 8;
    const int cb = blockIdx.x * 16;
    const int m0 = blockIdx.y * 256 + w * 64;
    int arow[4];
#pragma unroll
    for (int rf = 0; rf < 4; rf++) {
        int r = m0 + rf * 16 + lx;
        arow[rf] = (r < NROWS) ? r : NROWS - 1;
    }
    const f32x4 zf = {0.f, 0.f, 0.f, 0.f};
    f32x4 aI[4] = {zf, zf, zf, zf}, aO[4] = {zf, zf, zf, zf};
    f32x4 aU[4] = {zf, zf, zf, zf}, aF[4] = {zf, zf, zf, zf};

    for (int kb = 0; kb < 128; kb += 32) {
        short8 axh[4], axl[4];
#pragma unroll
        for (int rf = 0; rf < 4; rf++) {
            size_t xi = (size_t)arow[rf] * FDIM + kb + kl;
            axh[rf] = ldf(txh + xi);
            axl[rf] = ldf(txl + xi);
        }
        size_t bi = (size_t)(cb + lx) * 128 + kb + kl;
        {
            short8 bh = ldf(WxH + bi), bl = ldf(WxL + bi);
#pragma unroll
            for (int rf = 0; rf < 4; rf++) MF3(axh[rf], axl[rf], bh, bl, aI[rf]);
        }
        {
            short8 bh = ldf(WxH + bi + 32768), bl = ldf(WxL + bi + 32768);
#pragma unroll
            for (int rf = 0; rf < 4; rf++) MF3(axh[rf], axl[rf], bh, bl, aO[rf]);
        }
        {
            short8 bh = ldf(WxH + bi + 65536), bl = ldf(WxL + bi + 65536);
#pragma unroll
            for (int rf = 0; rf < 4; rf++) MF3(axh[rf], axl[rf], bh, bl, aU[rf]);
        }
        {
            short8 bh = ldf(WfxH + bi), bl = ldf(WfxL + bi);
#pragma unroll
            for (int rf = 0; rf < 4; rf++) MF3(axh[rf], axl[rf], bh, bl, aF[rf]);
        }
    }
    for (int kb = 0; kb < 256; kb += 32) {
        short8 axh[4], axl[4];
#pragma unroll
        for (int rf = 0; rf < 4; rf++) {
            size_t xi = (size_t)arow[rf] * H + kb + kl;
            axh[rf] = ldf(hpH + xi);
            axl[rf] = ldf(hpL + xi);
        }
        size_t bi = (size_t)(cb + lx) * 256 + kb + kl;
        {
            short8 bh = ldf(WhH + bi), bl = ldf(WhL + bi);
#pragma unroll
            for (int rf = 0; rf < 4; rf++) MF3(axh[rf], axl[rf], bh, bl, aI[rf]);
        }
        {
            short8 bh = ldf(WhH + bi + 65536), bl = ldf(WhL + bi + 65536);
#pragma unroll
            for (int rf = 0; rf < 4; rf++) MF3(axh[rf], axl[rf], bh, bl, aO[rf]);
        }
        {
            short8 bh = ldf(WhH + bi + 131072), bl = ldf(WhL + bi + 131072);
#pragma unroll
            for (int rf = 0; rf < 4; rf++) MF3(axh[rf], axl[rf], bh, bl, aU[rf]);
        }
        {
            short8 bh = ldf(WfhH + bi), bl = ldf(WfhL + bi);
#pragma unroll
            for (int rf = 0; rf < 4; rf++) MF3(axh[rf], axl[rf], bh, bl, aF[rf]);
        }
    }
    const int col = cb + lx;
    const float b_i = bioux[col] + biouh[col];
    const float b_o = bioux[256 + col] + biouh[256 + col];
    const float b_u = bioux[512 + col] + biouh[512 + col];
    const float b_f = bfx[col] + bfh[col];
#pragma unroll
    for (int rf = 0; rf < 4; rf++) {
#pragma unroll
        for (int rr = 0; rr < 4; rr++) {
            int row = m0 + rf * 16 + (lane >> 4) * 4 + rr;
            if (row < NROWS) {
                float ig = sigmoidf_(aI[rf][rr] + b_i);
                float og = sigmoidf_(aO[rf][rr] + b_o);
                float ug = tanhf(aU[rf][rr] + b_u);
                float fg = sigmoidf_(aF[rf][rr] + b_f);
                size_t ci = (size_t)row * H + col;
                float cnew = ig * ug + fg * cst[ci];
                cst[ci] = cnew;
                float hnew = og * tanhf(cnew);
                size_t oi = (size_t)row * oldv + col;
                u16 hh = f2bf(hnew);
                oH[oi] = hh;
                oL[oi] = f2bf(hnew - bf2f(hh));
            }
        }
    }
}

// fv += hf @ Wc[:,off_f:+256]^T + hb @ Wc[:,off_b:+256]^T  (wave 64x64)
__global__ __launch_bounds__(256) void k_fv_acc_mf(
    float* __restrict__ fv, const u16* __restrict__ hqH, const u16* __restrict__ hqL,
    const u16* __restrict__ WcH, const u16* __restrict__ WcL, int off_f, int off_b) {
    const int tid = threadIdx.x, lane = tid & 63, w = tid >> 6;
    const int lx = lane & 15, kl = (lane >> 4) * 8;
    const int cb = blockIdx.x * 64;
    const int m0 = blockIdx.y * 256 + w * 64;
    int arow[4];
#pragma unroll
    for (int rf = 0; rf < 4; rf++) {
        int r = m0 + rf * 16 + lx;
        arow[rf] = (r < NROWS) ? r : NROWS - 1;
    }
    const f32x4 zf = {0.f, 0.f, 0.f, 0.f};
    f32x4 acc[4][4] = {{zf, zf, zf, zf}, {zf, zf, zf, zf}, {zf, zf, zf, zf}, {zf, zf, zf, zf}};
    for (int ph = 0; ph < 2; ph++) {
        const u16* ah = hqH + (size_t)ph * NROWS * H;
        const u16* al = hqL + (size_t)ph * NROWS * H;
        const int off = ph ? off_b : off_f;
        for (int kb = 0; kb < 256; kb += 32) {
            short8 axh[4], axl[4];
#pragma unroll
            for (int rf = 0; rf < 4; rf++) {
                size_t xi = (size_t)arow[rf] * H + kb + kl;
                axh[rf] = ldf(ah + xi);
                axl[rf] = ldf(al + xi);
            }
#pragma unroll
            for (int cf = 0; cf < 4; cf++) {
                size_t bi = (size_t)(cb + cf * 16 + lx) * 2560 + off + kb + kl;
                short8 bh = ldf(WcH + bi), bl = ldf(WcL + bi);
#pragma unroll
                for (int rf = 0; rf < 4; rf++) MF3(axh[rf], axl[rf], bh, bl, acc[rf][cf]);
            }
        }
    }
#pragma unroll
    for (int rf = 0; rf < 4; rf++) {
#pragma unroll
        for (int cf = 0; cf < 4; cf++) {
            int col = cb + cf * 16 + lx;
#pragma unroll
            for (int rr = 0; rr < 4; rr++) {
                int row = m0 + rf * 16 + (lane >> 4) * 4 + rr;
                if (row < NROWS) fv[(size_t)row * H + col] += acc[rf][cf][rr];
            }
        }
    }
}

// xw = A @ W^T  (A pre-split hi/lo [N,256], W [256,256] hi/lo)
__global__ __launch_bounds__(256) void k_gcn_gemm(
    float* __restrict__ out, const u16* __restrict__ aH, const u16* __restrict__ aL,
    const u16* __restrict__ WH, const u16* __restrict__ WL) {
    const int tid = threadIdx.x, lane = tid & 63, w = tid >> 6;
    const int lx = lane & 15, kl = (lane >> 4) * 8;
    const int cb = blockIdx.x * 64;
    const int m0 = blockIdx.y * 256 + w * 64;
    int arow[4];
#pragma unroll
    for (int rf = 0; rf < 4; rf++) {
        int r = m0 + rf * 16 + lx;
        arow[rf] = (r < NROWS) ? r : NROWS - 1;
    }
    const f32x4 zf = {0.f, 0.f, 0.f, 0.f};
    f32x4 acc[4][4] = {{zf, zf, zf, zf}, {zf, zf, zf, zf}, {zf, zf, zf, zf}, {zf, zf, zf, zf}};
    for (int kb = 0; kb < 256; kb += 32) {
        short8 axh[4], axl[4];
#pragma unroll
        for (int rf = 0; rf < 4; rf++) {
            size_t xi = (size_t)arow[rf] * H + kb + kl;
            axh[rf] = ldf(aH + xi);
            axl[rf] = ldf(aL + xi);
        }
#pragma unroll
        for (int cf = 0; cf < 4; cf++) {
            size_t bi = (size_t)(cb + cf * 16 + lx) * 256 + kb + kl;
            short8 bh = ldf(WH + bi), bl = ldf(WL + bi);
#pragma unroll
            for (int rf = 0; rf < 4; rf++) MF3(axh[rf], axl[rf], bh, bl, acc[rf][cf]);
        }
    }
#pragma unroll
    for (int rf = 0; rf < 4; rf++) {
#pragma unroll
        for (int cf = 0; cf < 4; cf++) {
            int col = cb + cf * 16 + lx;
#pragma unroll
            for (int rr = 0; rr < 4; rr++) {
                int row = m0 + rf * 16 + (lane >> 4) * 4 + rr;
                if (row < NROWS) out[(size_t)row * H + col] = acc[rf][cf][rr];
            }
        }
    }
}

// ---------------------------- GCN small kernels -----------------------------
__global__ void k_fv_init(float* fv, const float* __restrict__ b) {
    int idx = blockIdx.x * 256 + threadIdx.x;
    if (idx < NROWS * H) fv[idx] = b[idx & (H - 1)];
}
__global__ void k_cnt(int* __restrict__ cnt, const int* __restrict__ dst) {
    int i = blockIdx.x * 256 + threadIdx.x;
    if (i < NE) atomicAdd(&cnt[dst[i]], 1);
}
__global__ void k_scan(const int* __restrict__ cnt, int* __restrict__ rowptr) {
    __shared__ int part[256];
    int tid = threadIdx.x;
    int st = tid * 40, en = (st + 40 > NROWS) ? NROWS : st + 40;
    int s = 0;
    for (int i = st; i < en; i++) s += cnt[i];
    part[tid] = s;
    __syncthreads();
    if (tid == 0) {
        int run = 0;
        for (int i = 0; i < 256; i++) { int t = part[i]; part[i] = run; run += t; }
        rowptr[NROWS] = run;
    }
    __syncthreads();
    int run = part[tid];
    for (int i = st; i < en; i++) { rowptr[i] = run; run += cnt[i]; }
}
__global__ void k_dinv(float* __restrict__ dinv, const int* __restrict__ cnt) {
    int i = blockIdx.x * 256 + threadIdx.x;
    if (i < NROWS) dinv[i] = rsqrtf(1.0f + (float)cnt[i]);
}
__global__ void k_fill(int* __restrict__ csr, int* __restrict__ cursor,
                       const int* __restrict__ rowptr, const int* __restrict__ ei) {
    int e = blockIdx.x * 256 + threadIdx.x;
    if (e < NE) {
        int d = ei[NE + e];
        int p = atomicAdd(&cursor[d], 1);
        csr[rowptr[d] + p] = ei[e];
    }
}
// out[node] = relu( dinv[n]^2*xw[n] + sum_e dinv[n]*dinv[s]*xw[s] + b )
__global__ __launch_bounds__(256) void k_gather(
    float* __restrict__ out, const float* __restrict__ xw, const float* __restrict__ dinv,
    const int* __restrict__ rowptr, const int* __restrict__ csr, const float* __restrict__ b) {
    int node = blockIdx.x * 4 + (threadIdx.x >> 6);
    if (node >= NROWS) return;
    int lane = threadIdx.x & 63;
    float dn = dinv[node];
    float4 acc = *(const float4*)(xw + (size_t)node * H + lane * 4);
    float dn2 = dn * dn;
    acc.x *= dn2; acc.y *= dn2; acc.z *= dn2; acc.w *= dn2;
    int e0 = rowptr[node], e1 = rowptr[node + 1];
    for (int i = e0; i < e1; i++) {
        int s = csr[i];
        float wgt = dn * dinv[s];
        const float4 v = *(const float4*)(xw + (size_t)s * H + lane * 4);
        acc.x += v.x * wgt; acc.y += v.y * wgt; acc.z += v.z * wgt; acc.w += v.w * wgt;
    }
    const float4 bv = *(const float4*)(b + lane * 4);
    float4 o;
    o.x = fmaxf(acc.x + bv.x, 0.f);
    o.y = fmaxf(acc.y + bv.y, 0.f);
    o.z = fmaxf(acc.z + bv.z, 0.f);
    o.w = fmaxf(acc.w + bv.w, 0.f);
    *(float4*)(out + (size_t)node * H + lane * 4) = o;
}
__global__ void k_colmax(float* __restrict__ out, const float* __restrict__ x) {
    int j = threadIdx.x;
    float m = 0.0f;
    for (int r = blockIdx.x; r < NROWS; r += gridDim.x)
        m = fmaxf(m, x[(size_t)r * H + j]);
    atomicMax((int*)&out[j], __float_as_int(m));
}

// ---------------------------------------------------------------------------
extern "C" void kernel_launch(void* const* d_in, const int* in_sizes, int n_in,
                              void* d_out, int out_size, void* d_ws, size_t ws_size,
                              hipStream_t stream) {
    const float* tree = (const float*)d_in[0];
    const float* s2 = (const float*)d_in[1];
    const float* s3 = (const float*)d_in[2];
    const float* s4 = (const float*)d_in[3];
    const float* s5 = (const float*)d_in[4];
    const int* edge = (const int*)d_in[5];
    const float* tl_Wioux = (const float*)d_in[6];
    const float* tl_bioux = (const float*)d_in[7];
    const float* tl_Wiouh = (const float*)d_in[8];
    const float* tl_biouh = (const float*)d_in[9];
    const float* tl_Wfx = (const float*)d_in[10];
    const float* tl_bfx = (const float*)d_in[11];
    const float* tl_Wfh = (const float*)d_in[12];
    const float* tl_bfh = (const float*)d_in[13];
    const float* gru_Wih = (const float*)d_in[14];
    const float* gru_Whh = (const float*)d_in[15];
    const float* gru_bih = (const float*)d_in[16];
    const float* gru_bhh = (const float*)d_in[17];
    const float* comb_Wih = (const float*)d_in[18];
    const float* comb_Whh = (const float*)d_in[19];
    const float* comb_bih = (const float*)d_in[20];
    const float* comb_bhh = (const float*)d_in[21];
    const float* connect_W = (const float*)d_in[22];
    const float* connect_b = (const float*)d_in[23];
    const float* gcn_W = (const float*)d_in[24];
    const float* gcn_b = (const float*)d_in[25];

    char* base = (char*)d_ws;
    size_t off = 0;
    auto aus = [&](size_t n) { u16* p = (u16*)(base + off); off += n * sizeof(u16); return p; };
    u16* txH = aus(98304);   u16* txL = aus(98304);
    u16* thH = aus(196608);  u16* thL = aus(196608);
    u16* tfxH = aus(32768);  u16* tfxL = aus(32768);
    u16* tfhH = aus(65536);  u16* tfhL = aus(65536);
    u16* gWihH = aus(393216); u16* gWihL = aus(393216);
    u16* gWhhH = aus(786432); u16* gWhhL = aus(786432);
    u16* cWihH = aus(393216); u16* cWihL = aus(393216);
    u16* cWhhH = aus(393216); u16* cWhhL = aus(393216);
    u16* cnH = aus(655360);  u16* cnL = aus(655360);
    u16* gcH = aus(196608);  u16* gcL = aus(196608);
    u16* featsH = aus((size_t)NROWS * 5 * H);
    u16* featsL = aus((size_t)NROWS * 5 * H);
    u16* hAH = aus((size_t)4 * NROWS * H);
    u16* hAL = aus((size_t)4 * NROWS * H);
    u16* hBH = aus((size_t)4 * NROWS * H);
    u16* hBL = aus((size_t)4 * NROWS * H);
    float* cbuf = (float*)(base + off); off += (size_t)NROWS * H * 4;
    float* fv = (float*)(base + off);   off += (size_t)NROWS * H * 4;

    const dim3 blk(256);
    const size_t NH = (size_t)NROWS * H;

    hipMemsetAsync(d_out, 0, H * sizeof(float), stream);

    // -------- split weights to bf16 hi/lo --------
    auto SP = [&](const float* s, u16* h, u16* l, int n) {
        k_split<<<(n + 255) / 256, blk, 0, stream>>>(s, h, l, n);
    };
    SP(tl_Wioux, txH, txL, 98304);
    SP(tl_Wiouh, thH, thL, 196608);
    SP(tl_Wfx, tfxH, tfxL, 32768);
    SP(tl_Wfh, tfhH, tfhL, 65536);
    SP(gru_Wih, gWihH, gWihL, 393216);
    SP(gru_Whh, gWhhH, gWhhL, 786432);
    SP(comb_Wih, cWihH, cWihL, 393216);
    SP(comb_Whh, cWhhH, cWhhL, 393216);
    SP(connect_W, cnH, cnL, 655360);
    SP(gcn_W, gcH, gcL, 196608);

    // -------- TreeLSTM (8 steps); x slice split into fv region --------
    hipMemsetAsync(hAH, 0, NH * 2, stream);
    hipMemsetAsync(hAL, 0, NH * 2, stream);
    hipMemsetAsync(cbuf, 0, NH * 4, stream);
    {
        u16* txsH = (u16*)fv;
        u16* txsL = txsH + (size_t)NROWS * FDIM;
        u16 *pH = hAH, *pL = hAL, *qH = hBH, *qL = hBL;
        for (int t = 0; t < LTREE; ++t) {
            bool last = (t == LTREE - 1);
            k_split_str<<<(NROWS * FDIM + 255) / 256, blk, 0, stream>>>(
                tree + t * FDIM, LTREE * FDIM, txsH, txsL);
            k_tree_step_mf<<<dim3(16, 40, 1), blk, 0, stream>>>(
                txsH, txsL, txH, txL, thH, thL, tfxH, tfxL, tfhH, tfhL,
                tl_bioux, tl_biouh, tl_bfx, tl_bfh, pH, pL, cbuf,
                last ? featsH : qH, last ? featsL : qL, last ? 5 * H : H);
            u16* t1 = pH; pH = qH; qH = t1;
            u16* t2 = pL; pL = qL; qL = t2;
        }
    }

    // -------- 4 GRUs (16 steps, z=4); x slices split into cbuf+fv regions ----
    hipMemsetAsync(hAH, 0, 4 * NH * 2, stream);
    hipMemsetAsync(hAL, 0, 4 * NH * 2, stream);
    {
        u16* xsH = (u16*)cbuf;  // 4*N*128 u16 = 10.24 MB, fits exactly
        u16* xsL = (u16*)fv;
        u16 *pH = hAH, *pL = hAL, *qH = hBH, *qL = hBL;
        for (int t = 0; t < TSEQ; ++t) {
            bool last = (t == TSEQ - 1);
            k_split_seq<<<dim3((NROWS * FDIM + 255) / 256, 1, 4), blk, 0, stream>>>(
                s2, s3, s4, s5, t, xsH, xsL);
            k_rnn_step<128><<<dim3(16, 40, 4), blk, 0, stream>>>(
                xsH, xsL, (long long)NROWS * FDIM, FDIM, 0, 0,
                gWihH, gWihL, 98304LL, gWhhH, gWhhL, 196608LL, gru_bih, gru_bhh,
                pH, pL, (long long)NROWS * H,
                last ? featsH + H : qH, last ? featsL + H : qL,
                last ? (long long)H : (long long)NROWS * H, last ? 5 * H : H, 0);
            u16* t1 = pH; pH = qH; qH = t1;
            u16* t2 = pL; pL = qL; qL = t2;
        }
    }

    // -------- combine bi-GRU (5 steps, z=2) + fused connect --------
    hipMemsetAsync(hAH, 0, 2 * NH * 2, stream);
    hipMemsetAsync(hAL, 0, 2 * NH * 2, stream);
    k_fv_init<<<(NROWS * H + 255) / 256, blk, 0, stream>>>(fv, connect_b);
    {
        u16 *pH = hAH, *pL = hAL, *qH = hBH, *qL = hBL;
        for (int s = 0; s < 5; ++s) {
            k_rnn_step<256><<<dim3(16, 40, 2), blk, 0, stream>>>(
                featsH, featsL, 0LL, 5 * H, s * H, (4 - s) * H,
                cWihH, cWihL, 196608LL, cWhhH, cWhhL, 196608LL, comb_bih, comb_bhh,
                pH, pL, (long long)NROWS * H,
                qH, qL, (long long)NROWS * H, H, 0);
            k_fv_acc_mf<<<dim3(4, 40, 1), blk, 0, stream>>>(
                fv, qH, qL, cnH, cnL, s * 512, (4 - s) * 512 + 256);
            u16* t1 = pH; pH = qH; qH = t1;
            u16* t2 = pL; pL = qL; qL = t2;
        }
    }

    // -------- CSR build (hBL region is free now) --------
    int* cnt = (int*)hBL;
    int* rowptr = cnt + 10016;
    int* cursor = rowptr + 10016;
    int* csr = cursor + 10016;
    float* dinv = (float*)(csr + NE);
    hipMemsetAsync(cnt, 0, NROWS * sizeof(int), stream);
    hipMemsetAsync(cursor, 0, NROWS * sizeof(int), stream);
    k_cnt<<<(NE + 255) / 256, blk, 0, stream>>>(cnt, edge + NE);
    k_scan<<<1, blk, 0, stream>>>(cnt, rowptr);
    k_dinv<<<(NROWS + 255) / 256, blk, 0, stream>>>(dinv, cnt);
    k_fill<<<(NE + 255) / 256, blk, 0, stream>>>(csr, cursor, rowptr, edge);

    // -------- 4 conv applications (last two share W2,b2) --------
    {
        u16* xcH = hBH;
        u16* xcL = hBH + NH;
        float* xw = (float*)hAH;
        float* xb = (float*)hAL;
        float* cur = fv;
        float* nxt = xb;
        for (int i = 0; i < 4; ++i) {
            int wi = (i < 3) ? i : 2;
            k_split<<<(NROWS * H + 255) / 256, blk, 0, stream>>>(cur, xcH, xcL, NROWS * H);
            k_gcn_gemm<<<dim3(4, 40, 1), blk, 0, stream>>>(xw, xcH, xcL,
                                                           gcH + wi * 65536, gcL + wi * 65536);
            k_gather<<<(NROWS + 3) / 4, blk, 0, stream>>>(nxt, xw, dinv, rowptr, csr,
                                                          gcn_b + wi * H);
            float* tmp = cur; cur = nxt; nxt = tmp;
        }
        k_colmax<<<256, blk, 0, stream>>>((float*)d_out, cur);
    }
}

// Round 4
// 5702.267 us; speedup vs baseline: 3.6756x; 1.0928x over previous
//
#include <hip/hip_runtime.h>
#include <math.h>

#define H 256
#define NROWS 10000
#define LTREE 8
#define TSEQ 16
#define FDIM 128
#define NE 160000

typedef __attribute__((ext_vector_type(8))) short short8;
typedef __attribute__((ext_vector_type(4))) float f32x4;
typedef unsigned short u16;

__device__ __forceinline__ float sigmoidf_(float x) { return 1.0f / (1.0f + expf(-x)); }
__device__ __forceinline__ u16 f2bf(float x) {
    unsigned int u = __float_as_uint(x);
    return (u16)((u + 0x7fffu + ((u >> 16) & 1u)) >> 16);
}
__device__ __forceinline__ float bf2f(u16 s) { return __uint_as_float(((unsigned int)s) << 16); }
__device__ __forceinline__ short8 ldf(const u16* __restrict__ p) { return *(const short8*)(p); }
#define MFMA(A, B, C) C = __builtin_amdgcn_mfma_f32_16x16x32_bf16(A, B, C, 0, 0, 0)
#define MF3(AH, AL, BH, BL, C) do { MFMA(AH, BH, C); MFMA(AL, BH, C); MFMA(AH, BL, C); } while (0)

// XCD-aware block remap: group all column-blocks of one (row-group, z) on one
// XCD (default dispatch is round-robin bid%8 across XCDs); z-major grouping so
// weights stay L2-resident per XCD. Requires gx*gy*gz % 8 == 0 and gy*gz % 8 == 0.
__device__ __forceinline__ void xcd_swz(int& cbi, int& yy, int& zz) {
    const int gx = gridDim.x, gy = gridDim.y, gz = gridDim.z;
    int bid = blockIdx.x + gx * (blockIdx.y + gy * blockIdx.z);
    int xcd = bid & 7;
    int slot = bid >> 3;
    int gpx = (gy * gz) >> 3;
    int grp = xcd * gpx + slot / gx;
    cbi = slot % gx;
    zz = grp / gy;
    yy = grp % gy;
}

// -------------------- split helpers --------------------
__global__ void k_split(const float* __restrict__ src, u16* __restrict__ hi,
                        u16* __restrict__ lo, int n) {
    int i = blockIdx.x * 256 + threadIdx.x;
    if (i < n) {
        float x = src[i];
        u16 h = f2bf(x);
        hi[i] = h;
        lo[i] = f2bf(x - bf2f(h));
    }
}
__global__ void k_split_str(const float* __restrict__ src, int ld,
                            u16* __restrict__ oh, u16* __restrict__ ol) {
    int idx = blockIdx.x * 256 + threadIdx.x;
    if (idx < NROWS * FDIM) {
        int row = idx >> 7, col = idx & 127;
        float v = src[(size_t)row * ld + col];
        u16 h = f2bf(v);
        oh[idx] = h;
        ol[idx] = f2bf(v - bf2f(h));
    }
}
__global__ void k_split_seq(const float* __restrict__ s2, const float* __restrict__ s3,
                            const float* __restrict__ s4, const float* __restrict__ s5,
                            int t, u16* __restrict__ oh, u16* __restrict__ ol) {
    int idx = blockIdx.x * 256 + threadIdx.x;
    int z = blockIdx.z;
    if (idx < NROWS * FDIM) {
        const float* s = (z == 0) ? s2 : (z == 1) ? s3 : (z == 2) ? s4 : s5;
        int row = idx >> 7, col = idx & 127;
        float v = s[(size_t)row * (TSEQ * FDIM) + t * FDIM + col];
        u16 h = f2bf(v);
        size_t oi = (size_t)z * NROWS * FDIM + idx;
        oh[oi] = h;
        ol[oi] = f2bf(v - bf2f(h));
    }
}

// ---------------------------------------------------------------------------
// GRU step, register-blocked + XCD-swizzled.
// ---------------------------------------------------------------------------
template <int KX>
__global__ __launch_bounds__(256) void k_rnn_step(
    const u16* __restrict__ fxh, const u16* __restrict__ fxl,
    long long xzs, int xld, int xc0, int xc1,
    const u16* __restrict__ WihH, const u16* __restrict__ WihL, long long wz,
    const u16* __restrict__ WhhH, const u16* __restrict__ WhhL, long long wzh,
    const float* __restrict__ bihB, const float* __restrict__ bhhB,
    const u16* __restrict__ hpH, const u16* __restrict__ hpL, long long hz,
    u16* __restrict__ oH, u16* __restrict__ oL, long long ozs, int oldv, int ocoff) {
    const int tid = threadIdx.x, lane = tid & 63, w = tid >> 6;
    const int lx = lane & 15, kl = (lane >> 4) * 8;
    int cbi, yy, z;
    xcd_swz(cbi, yy, z);
    const int cb = cbi * 16;
    const int m0 = yy * 256 + w * 64;
    int arow[4];
#pragma unroll
    for (int rf = 0; rf < 4; rf++) {
        int r = m0 + rf * 16 + lx;
        arow[rf] = (r < NROWS) ? r : NROWS - 1;
    }
    const u16* xh = fxh + (size_t)z * xzs;
    const u16* xl = fxl + (size_t)z * xzs;
    const int xco = (z == 1) ? xc1 : xc0;
    const u16* WihHz = WihH + (size_t)z * wz;
    const u16* WihLz = WihL + (size_t)z * wz;
    const u16* WhhHz = WhhH + (size_t)z * wzh;
    const u16* WhhLz = WhhL + (size_t)z * wzh;
    const float* bih = bihB + z * 768;
    const float* bhh = bhhB + z * 768;
    const u16* hph = hpH + (size_t)z * hz;
    const u16* hpl = hpL + (size_t)z * hz;

    const f32x4 zf = {0.f, 0.f, 0.f, 0.f};
    f32x4 aR[4] = {zf, zf, zf, zf}, aZ[4] = {zf, zf, zf, zf};
    f32x4 aNX[4] = {zf, zf, zf, zf}, aNH[4] = {zf, zf, zf, zf};

    for (int kb = 0; kb < KX; kb += 32) {
        short8 axh[4], axl[4];
#pragma unroll
        for (int rf = 0; rf < 4; rf++) {
            size_t xi = (size_t)arow[rf] * xld + xco + kb + kl;
            axh[rf] = ldf(xh + xi);
            axl[rf] = ldf(xl + xi);
        }
        size_t bi = (size_t)(cb + lx) * KX + kb + kl;
        {
            short8 bh = ldf(WihHz + bi), bl = ldf(WihLz + bi);
#pragma unroll
            for (int rf = 0; rf < 4; rf++) MF3(axh[rf], axl[rf], bh, bl, aR[rf]);
        }
        {
            short8 bh = ldf(WihHz + bi + (size_t)256 * KX), bl = ldf(WihLz + bi + (size_t)256 * KX);
#pragma unroll
            for (int rf = 0; rf < 4; rf++) MF3(axh[rf], axl[rf], bh, bl, aZ[rf]);
        }
        {
            short8 bh = ldf(WihHz + bi + (size_t)512 * KX), bl = ldf(WihLz + bi + (size_t)512 * KX);
#pragma unroll
            for (int rf = 0; rf < 4; rf++) MF3(axh[rf], axl[rf], bh, bl, aNX[rf]);
        }
    }
    for (int kb = 0; kb < 256; kb += 32) {
        short8 axh[4], axl[4];
#pragma unroll
        for (int rf = 0; rf < 4; rf++) {
            size_t xi = (size_t)arow[rf] * H + kb + kl;
            axh[rf] = ldf(hph + xi);
            axl[rf] = ldf(hpl + xi);
        }
        size_t bi = (size_t)(cb + lx) * 256 + kb + kl;
        {
            short8 bh = ldf(WhhHz + bi), bl = ldf(WhhLz + bi);
#pragma unroll
            for (int rf = 0; rf < 4; rf++) MF3(axh[rf], axl[rf], bh, bl, aR[rf]);
        }
        {
            short8 bh = ldf(WhhHz + bi + 65536), bl = ldf(WhhLz + bi + 65536);
#pragma unroll
            for (int rf = 0; rf < 4; rf++) MF3(axh[rf], axl[rf], bh, bl, aZ[rf]);
        }
        {
            short8 bh = ldf(WhhHz + bi + 131072), bl = ldf(WhhLz + bi + 131072);
#pragma unroll
            for (int rf = 0; rf < 4; rf++) MF3(axh[rf], axl[rf], bh, bl, aNH[rf]);
        }
    }
    const int col = cb + lx;
    const float b_r = bih[col] + bhh[col];
    const float b_z = bih[256 + col] + bhh[256 + col];
    const float bx_n = bih[512 + col], bh_n = bhh[512 + col];
#pragma unroll
    for (int rf = 0; rf < 4; rf++) {
#pragma unroll
        for (int rr = 0; rr < 4; rr++) {
            int row = m0 + rf * 16 + (lane >> 4) * 4 + rr;
            if (row < NROWS) {
                float rg = sigmoidf_(aR[rf][rr] + b_r);
                float zg = sigmoidf_(aZ[rf][rr] + b_z);
                float ng = tanhf(aNX[rf][rr] + bx_n + rg * (aNH[rf][rr] + bh_n));
                size_t hidx = (size_t)row * H + col;
                float hold = bf2f(hph[hidx]) + bf2f(hpl[hidx]);
                float hnew = (1.0f - zg) * ng + zg * hold;
                size_t oi = (size_t)z * ozs + (size_t)row * oldv + ocoff + col;
                u16 hh = f2bf(hnew);
                oH[oi] = hh;
                oL[oi] = f2bf(hnew - bf2f(hh));
            }
        }
    }
}

// ---------------------------------------------------------------------------
// TreeLSTM step (chain), XCD-swizzled.
// ---------------------------------------------------------------------------
__global__ __launch_bounds__(256) void k_tree_step_mf(
    const u16* __restrict__ txh, const u16* __restrict__ txl,
    const u16* __restrict__ WxH, const u16* __restrict__ WxL,
    const u16* __restrict__ WhH, const u16* __restrict__ WhL,
    const u16* __restrict__ WfxH, const u16* __restrict__ WfxL,
    const u16* __restrict__ WfhH, const u16* __restrict__ WfhL,
    const float* __restrict__ bioux, const float* __restrict__ biouh,
    const float* __restrict__ bfx, const float* __restrict__ bfh,
    const u16* __restrict__ hpH, const u16* __restrict__ hpL,
    float* __restrict__ cst, u16* __restrict__ oH, u16* __restrict__ oL, int oldv) {
    const int tid = threadIdx.x, lane = tid & 63, w = tid >> 6;
    const int lx = lane & 15, kl = (lane >> 4) * 8;
    int cbi, yy, zz;
    xcd_swz(cbi, yy, zz);
    const int cb = cbi * 16;
    const int m0 = yy * 256 + w * 64;
    int arow[4];
#pragma unroll
    for (int rf = 0; rf < 4; rf++) {
        int r = m0 + rf * 16 + lx;
        arow[rf] = (r < NROWS) ? r : NROWS - 1;
    }
    const f32x4 zf = {0.f, 0.f, 0.f, 0.f};
    f32x4 aI[4] = {zf, zf, zf, zf}, aO[4] = {zf, zf, zf, zf};
    f32x4 aU[4] = {zf, zf, zf, zf}, aF[4] = {zf, zf, zf, zf};

    for (int kb = 0; kb < 128; kb += 32) {
        short8 axh[4], axl[4];
#pragma unroll
        for (int rf = 0; rf < 4; rf++) {
            size_t xi = (size_t)arow[rf] * FDIM + kb + kl;
            axh[rf] = ldf(txh + xi);
            axl[rf] = ldf(txl + xi);
        }
        size_t bi = (size_t)(cb + lx) * 128 + kb + kl;
        {
            short8 bh = ldf(WxH + bi), bl = ldf(WxL + bi);
#pragma unroll
            for (int rf = 0; rf < 4; rf++) MF3(axh[rf], axl[rf], bh, bl, aI[rf]);
        }
        {
            short8 bh = ldf(WxH + bi + 32768), bl = ldf(WxL + bi + 32768);
#pragma unroll
            for (int rf = 0; rf < 4; rf++) MF3(axh[rf], axl[rf], bh, bl, aO[rf]);
        }
        {
            short8 bh = ldf(WxH + bi + 65536), bl = ldf(WxL + bi + 65536);
#pragma unroll
            for (int rf = 0; rf < 4; rf++) MF3(axh[rf], axl[rf], bh, bl, aU[rf]);
        }
        {
            short8 bh = ldf(WfxH + bi), bl = ldf(WfxL + bi);
#pragma unroll
            for (int rf = 0; rf < 4; rf++) MF3(axh[rf], axl[rf], bh, bl, aF[rf]);
        }
    }
    for (int kb = 0; kb < 256; kb += 32) {
        short8 axh[4], axl[4];
#pragma unroll
        for (int rf = 0; rf < 4; rf++) {
            size_t xi = (size_t)arow[rf] * H + kb + kl;
            axh[rf] = ldf(hpH + xi);
            axl[rf] = ldf(hpL + xi);
        }
        size_t bi = (size_t)(cb + lx) * 256 + kb + kl;
        {
            short8 bh = ldf(WhH + bi), bl = ldf(WhL + bi);
#pragma unroll
            for (int rf = 0; rf < 4; rf++) MF3(axh[rf], axl[rf], bh, bl, aI[rf]);
        }
        {
            short8 bh = ldf(WhH + bi + 65536), bl = ldf(WhL + bi + 65536);
#pragma unroll
            for (int rf = 0; rf < 4; rf++) MF3(axh[rf], axl[rf], bh, bl, aO[rf]);
        }
        {
            short8 bh = ldf(WhH + bi + 131072), bl = ldf(WhL + bi + 131072);
#pragma unroll
            for (int rf = 0; rf < 4; rf++) MF3(axh[rf], axl[rf], bh, bl, aU[rf]);
        }
        {
            short8 bh = ldf(WfhH + bi), bl = ldf(WfhL + bi);
#pragma unroll
            for (int rf = 0; rf < 4; rf++) MF3(axh[rf], axl[rf], bh, bl, aF[rf]);
        }
    }
    const int col = cb + lx;
    const float b_i = bioux[col] + biouh[col];
    const float b_o = bioux[256 + col] + biouh[256 + col];
    const float b_u = bioux[512 + col] + biouh[512 + col];
    const float b_f = bfx[col] + bfh[col];
#pragma unroll
    for (int rf = 0; rf < 4; rf++) {
#pragma unroll
        for (int rr = 0; rr < 4; rr++) {
            int row = m0 + rf * 16 + (lane >> 4) * 4 + rr;
            if (row < NROWS) {
                float ig = sigmoidf_(aI[rf][rr] + b_i);
                float og = sigmoidf_(aO[rf][rr] + b_o);
                float ug = tanhf(aU[rf][rr] + b_u);
                float fg = sigmoidf_(aF[rf][rr] + b_f);
                size_t ci = (size_t)row * H + col;
                float cnew = ig * ug + fg * cst[ci];
                cst[ci] = cnew;
                float hnew = og * tanhf(cnew);
                size_t oi = (size_t)row * oldv + col;
                u16 hh = f2bf(hnew);
                oH[oi] = hh;
                oL[oi] = f2bf(hnew - bf2f(hh));
            }
        }
    }
}

// fv += hf @ Wc[:,off_f:+256]^T + hb @ Wc[:,off_b:+256]^T  (wave 64x64, swz)
__global__ __launch_bounds__(256) void k_fv_acc_mf(
    float* __restrict__ fv, const u16* __restrict__ hqH, const u16* __restrict__ hqL,
    const u16* __restrict__ WcH, const u16* __restrict__ WcL, int off_f, int off_b) {
    const int tid = threadIdx.x, lane = tid & 63, w = tid >> 6;
    const int lx = lane & 15, kl = (lane >> 4) * 8;
    int cbi, yy, zz;
    xcd_swz(cbi, yy, zz);
    const int cb = cbi * 64;
    const int m0 = yy * 256 + w * 64;
    int arow[4];
#pragma unroll
    for (int rf = 0; rf < 4; rf++) {
        int r = m0 + rf * 16 + lx;
        arow[rf] = (r < NROWS) ? r : NROWS - 1;
    }
    const f32x4 zf = {0.f, 0.f, 0.f, 0.f};
    f32x4 acc[4][4] = {{zf, zf, zf, zf}, {zf, zf, zf, zf}, {zf, zf, zf, zf}, {zf, zf, zf, zf}};
    for (int ph = 0; ph < 2; ph++) {
        const u16* ah = hqH + (size_t)ph * NROWS * H;
        const u16* al = hqL + (size_t)ph * NROWS * H;
        const int off = ph ? off_b : off_f;
        for (int kb = 0; kb < 256; kb += 32) {
            short8 axh[4], axl[4];
#pragma unroll
            for (int rf = 0; rf < 4; rf++) {
                size_t xi = (size_t)arow[rf] * H + kb + kl;
                axh[rf] = ldf(ah + xi);
                axl[rf] = ldf(al + xi);
            }
#pragma unroll
            for (int cf = 0; cf < 4; cf++) {
                size_t bi = (size_t)(cb + cf * 16 + lx) * 2560 + off + kb + kl;
                short8 bh = ldf(WcH + bi), bl = ldf(WcL + bi);
#pragma unroll
                for (int rf = 0; rf < 4; rf++) MF3(axh[rf], axl[rf], bh, bl, acc[rf][cf]);
            }
        }
    }
#pragma unroll
    for (int rf = 0; rf < 4; rf++) {
#pragma unroll
        for (int cf = 0; cf < 4; cf++) {
            int col = cb + cf * 16 + lx;
#pragma unroll
            for (int rr = 0; rr < 4; rr++) {
                int row = m0 + rf * 16 + (lane >> 4) * 4 + rr;
                if (row < NROWS) fv[(size_t)row * H + col] += acc[rf][cf][rr];
            }
        }
    }
}

// xw = A @ W^T  (A pre-split hi/lo [N,256], W [256,256] hi/lo, swz)
__global__ __launch_bounds__(256) void k_gcn_gemm(
    float* __restrict__ out, const u16* __restrict__ aH, const u16* __restrict__ aL,
    const u16* __restrict__ WH, const u16* __restrict__ WL) {
    const int tid = threadIdx.x, lane = tid & 63, w = tid >> 6;
    const int lx = lane & 15, kl = (lane >> 4) * 8;
    int cbi, yy, zz;
    xcd_swz(cbi, yy, zz);
    const int cb = cbi * 64;
    const int m0 = yy * 256 + w * 64;
    int arow[4];
#pragma unroll
    for (int rf = 0; rf < 4; rf++) {
        int r = m0 + rf * 16 + lx;
        arow[rf] = (r < NROWS) ? r : NROWS - 1;
    }
    const f32x4 zf = {0.f, 0.f, 0.f, 0.f};
    f32x4 acc[4][4] = {{zf, zf, zf, zf}, {zf, zf, zf, zf}, {zf, zf, zf, zf}, {zf, zf, zf, zf}};
    for (int kb = 0; kb < 256; kb += 32) {
        short8 axh[4], axl[4];
#pragma unroll
        for (int rf = 0; rf < 4; rf++) {
            size_t xi = (size_t)arow[rf] * H + kb + kl;
            axh[rf] = ldf(aH + xi);
            axl[rf] = ldf(aL + xi);
        }
#pragma unroll
        for (int cf = 0; cf < 4; cf++) {
            size_t bi = (size_t)(cb + cf * 16 + lx) * 256 + kb + kl;
            short8 bh = ldf(WH + bi), bl = ldf(WL + bi);
#pragma unroll
            for (int rf = 0; rf < 4; rf++) MF3(axh[rf], axl[rf], bh, bl, acc[rf][cf]);
        }
    }
#pragma unroll
    for (int rf = 0; rf < 4; rf++) {
#pragma unroll
        for (int cf = 0; cf < 4; cf++) {
            int col = cb + cf * 16 + lx;
#pragma unroll
            for (int rr = 0; rr < 4; rr++) {
                int row = m0 + rf * 16 + (lane >> 4) * 4 + rr;
                if (row < NROWS) out[(size_t)row * H + col] = acc[rf][cf][rr];
            }
        }
    }
}

// ---------------------------- GCN small kernels -----------------------------
__global__ void k_fv_init(float* fv, const float* __restrict__ b) {
    int idx = blockIdx.x * 256 + threadIdx.x;
    if (idx < NROWS * H) fv[idx] = b[idx & (H - 1)];
}
__global__ void k_cnt(int* __restrict__ cnt, const int* __restrict__ dst) {
    int i = blockIdx.x * 256 + threadIdx.x;
    if (i < NE) atomicAdd(&cnt[dst[i]], 1);
}
__global__ void k_scan(const int* __restrict__ cnt, int* __restrict__ rowptr) {
    __shared__ int part[256];
    int tid = threadIdx.x;
    int st = tid * 40, en = (st + 40 > NROWS) ? NROWS : st + 40;
    int s = 0;
    for (int i = st; i < en; i++) s += cnt[i];
    part[tid] = s;
    __syncthreads();
    if (tid == 0) {
        int run = 0;
        for (int i = 0; i < 256; i++) { int t = part[i]; part[i] = run; run += t; }
        rowptr[NROWS] = run;
    }
    __syncthreads();
    int run = part[tid];
    for (int i = st; i < en; i++) { rowptr[i] = run; run += cnt[i]; }
}
__global__ void k_dinv(float* __restrict__ dinv, const int* __restrict__ cnt) {
    int i = blockIdx.x * 256 + threadIdx.x;
    if (i < NROWS) dinv[i] = rsqrtf(1.0f + (float)cnt[i]);
}
__global__ void k_fill(int* __restrict__ csr, int* __restrict__ cursor,
                       const int* __restrict__ rowptr, const int* __restrict__ ei) {
    int e = blockIdx.x * 256 + threadIdx.x;
    if (e < NE) {
        int d = ei[NE + e];
        int p = atomicAdd(&cursor[d], 1);
        csr[rowptr[d] + p] = ei[e];
    }
}
// out[node] = relu(...); also emits bf16 hi/lo split of out for the next conv
__global__ __launch_bounds__(256) void k_gather(
    float* __restrict__ out, u16* __restrict__ outH, u16* __restrict__ outL,
    const float* __restrict__ xw, const float* __restrict__ dinv,
    const int* __restrict__ rowptr, const int* __restrict__ csr, const float* __restrict__ b) {
    int node = blockIdx.x * 4 + (threadIdx.x >> 6);
    if (node >= NROWS) return;
    int lane = threadIdx.x & 63;
    float dn = dinv[node];
    float4 acc = *(const float4*)(xw + (size_t)node * H + lane * 4);
    float dn2 = dn * dn;
    acc.x *= dn2; acc.y *= dn2; acc.z *= dn2; acc.w *= dn2;
    int e0 = rowptr[node], e1 = rowptr[node + 1];
    for (int i = e0; i < e1; i++) {
        int s = csr[i];
        float wgt = dn * dinv[s];
        const float4 v = *(const float4*)(xw + (size_t)s * H + lane * 4);
        acc.x += v.x * wgt; acc.y += v.y * wgt; acc.z += v.z * wgt; acc.w += v.w * wgt;
    }
    const float4 bv = *(const float4*)(b + lane * 4);
    float o[4];
    o[0] = fmaxf(acc.x + bv.x, 0.f);
    o[1] = fmaxf(acc.y + bv.y, 0.f);
    o[2] = fmaxf(acc.z + bv.z, 0.f);
    o[3] = fmaxf(acc.w + bv.w, 0.f);
    *(float4*)(out + (size_t)node * H + lane * 4) = *(const float4*)o;
    u16 hs[4], ls[4];
#pragma unroll
    for (int j = 0; j < 4; j++) {
        hs[j] = f2bf(o[j]);
        ls[j] = f2bf(o[j] - bf2f(hs[j]));
    }
    *(short4*)(outH + (size_t)node * H + lane * 4) = *(const short4*)hs;
    *(short4*)(outL + (size_t)node * H + lane * 4) = *(const short4*)ls;
}
__global__ void k_colmax(float* __restrict__ out, const float* __restrict__ x) {
    int j = threadIdx.x;
    float m = 0.0f;
    for (int r = blockIdx.x; r < NROWS; r += gridDim.x)
        m = fmaxf(m, x[(size_t)r * H + j]);
    atomicMax((int*)&out[j], __float_as_int(m));
}

// ---------------------------------------------------------------------------
extern "C" void kernel_launch(void* const* d_in, const int* in_sizes, int n_in,
                              void* d_out, int out_size, void* d_ws, size_t ws_size,
                              hipStream_t stream) {
    const float* tree = (const float*)d_in[0];
    const float* s2 = (const float*)d_in[1];
    const float* s3 = (const float*)d_in[2];
    const float* s4 = (const float*)d_in[3];
    const float* s5 = (const float*)d_in[4];
    const int* edge = (const int*)d_in[5];
    const float* tl_Wioux = (const float*)d_in[6];
    const float* tl_bioux = (const float*)d_in[7];
    const float* tl_Wiouh = (const float*)d_in[8];
    const float* tl_biouh = (const float*)d_in[9];
    const float* tl_Wfx = (const float*)d_in[10];
    const float* tl_bfx = (const float*)d_in[11];
    const float* tl_Wfh = (const float*)d_in[12];
    const float* tl_bfh = (const float*)d_in[13];
    const float* gru_Wih = (const float*)d_in[14];
    const float* gru_Whh = (const float*)d_in[15];
    const float* gru_bih = (const float*)d_in[16];
    const float* gru_bhh = (const float*)d_in[17];
    const float* comb_Wih = (const float*)d_in[18];
    const float* comb_Whh = (const float*)d_in[19];
    const float* comb_bih = (const float*)d_in[20];
    const float* comb_bhh = (const float*)d_in[21];
    const float* connect_W = (const float*)d_in[22];
    const float* connect_b = (const float*)d_in[23];
    const float* gcn_W = (const float*)d_in[24];
    const float* gcn_b = (const float*)d_in[25];

    char* base = (char*)d_ws;
    size_t off = 0;
    auto aus = [&](size_t n) { u16* p = (u16*)(base + off); off += n * sizeof(u16); return p; };
    u16* txH = aus(98304);   u16* txL = aus(98304);
    u16* thH = aus(196608);  u16* thL = aus(196608);
    u16* tfxH = aus(32768);  u16* tfxL = aus(32768);
    u16* gWihH = aus(393216); u16* gWihL = aus(393216);
    u16* gWhhH = aus(786432); u16* gWhhL = aus(786432);
    u16* cWihH = aus(393216); u16* cWihL = aus(393216);
    u16* cWhhH = aus(393216); u16* cWhhL = aus(393216);
    u16* cnH = aus(655360);  u16* cnL = aus(655360);
    u16* gcH = aus(196608);  u16* gcL = aus(196608);
    u16* tfhH = aus(65536);  u16* tfhL = aus(65536);
    u16* featsH = aus((size_t)NROWS * 5 * H);
    u16* featsL = aus((size_t)NROWS * 5 * H);
    u16* hAH = aus((size_t)4 * NROWS * H);
    u16* hAL = aus((size_t)4 * NROWS * H);
    u16* hBH = aus((size_t)4 * NROWS * H);
    u16* hBL = aus((size_t)4 * NROWS * H);
    float* cbuf = (float*)(base + off); off += (size_t)NROWS * H * 4;
    float* fv = (float*)(base + off);   off += (size_t)NROWS * H * 4;

    const dim3 blk(256);
    const size_t NH = (size_t)NROWS * H;

    hipMemsetAsync(d_out, 0, H * sizeof(float), stream);

    auto SP = [&](const float* s, u16* h, u16* l, int n) {
        k_split<<<(n + 255) / 256, blk, 0, stream>>>(s, h, l, n);
    };
    SP(tl_Wioux, txH, txL, 98304);
    SP(tl_Wiouh, thH, thL, 196608);
    SP(tl_Wfx, tfxH, tfxL, 32768);
    SP(tl_Wfh, tfhH, tfhL, 65536);
    SP(gru_Wih, gWihH, gWihL, 393216);
    SP(gru_Whh, gWhhH, gWhhL, 786432);
    SP(comb_Wih, cWihH, cWihL, 393216);
    SP(comb_Whh, cWhhH, cWhhL, 393216);
    SP(connect_W, cnH, cnL, 655360);
    SP(gcn_W, gcH, gcL, 196608);

    // -------- TreeLSTM (8 steps) --------
    hipMemsetAsync(hAH, 0, NH * 2, stream);
    hipMemsetAsync(hAL, 0, NH * 2, stream);
    hipMemsetAsync(cbuf, 0, NH * 4, stream);
    {
        u16* txsH = (u16*)fv;
        u16* txsL = txsH + (size_t)NROWS * FDIM;
        u16 *pH = hAH, *pL = hAL, *qH = hBH, *qL = hBL;
        for (int t = 0; t < LTREE; ++t) {
            bool last = (t == LTREE - 1);
            k_split_str<<<(NROWS * FDIM + 255) / 256, blk, 0, stream>>>(
                tree + t * FDIM, LTREE * FDIM, txsH, txsL);
            k_tree_step_mf<<<dim3(16, 40, 1), blk, 0, stream>>>(
                txsH, txsL, txH, txL, thH, thL, tfxH, tfxL, tfhH, tfhL,
                tl_bioux, tl_biouh, tl_bfx, tl_bfh, pH, pL, cbuf,
                last ? featsH : qH, last ? featsL : qL, last ? 5 * H : H);
            u16* t1 = pH; pH = qH; qH = t1;
            u16* t2 = pL; pL = qL; qL = t2;
        }
    }

    // -------- 4 GRUs (16 steps, z=4) --------
    hipMemsetAsync(hAH, 0, 4 * NH * 2, stream);
    hipMemsetAsync(hAL, 0, 4 * NH * 2, stream);
    {
        u16* xsH = (u16*)cbuf;
        u16* xsL = (u16*)fv;
        u16 *pH = hAH, *pL = hAL, *qH = hBH, *qL = hBL;
        for (int t = 0; t < TSEQ; ++t) {
            bool last = (t == TSEQ - 1);
            k_split_seq<<<dim3((NROWS * FDIM + 255) / 256, 1, 4), blk, 0, stream>>>(
                s2, s3, s4, s5, t, xsH, xsL);
            k_rnn_step<128><<<dim3(16, 40, 4), blk, 0, stream>>>(
                xsH, xsL, (long long)NROWS * FDIM, FDIM, 0, 0,
                gWihH, gWihL, 98304LL, gWhhH, gWhhL, 196608LL, gru_bih, gru_bhh,
                pH, pL, (long long)NROWS * H,
                last ? featsH + H : qH, last ? featsL + H : qL,
                last ? (long long)H : (long long)NROWS * H, last ? 5 * H : H, 0);
            u16* t1 = pH; pH = qH; qH = t1;
            u16* t2 = pL; pL = qL; qL = t2;
        }
    }

    // -------- combine bi-GRU (5 steps, z=2) + fused connect --------
    hipMemsetAsync(hAH, 0, 2 * NH * 2, stream);
    hipMemsetAsync(hAL, 0, 2 * NH * 2, stream);
    k_fv_init<<<(NROWS * H + 255) / 256, blk, 0, stream>>>(fv, connect_b);
    {
        u16 *pH = hAH, *pL = hAL, *qH = hBH, *qL = hBL;
        for (int s = 0; s < 5; ++s) {
            k_rnn_step<256><<<dim3(16, 40, 2), blk, 0, stream>>>(
                featsH, featsL, 0LL, 5 * H, s * H, (4 - s) * H,
                cWihH, cWihL, 196608LL, cWhhH, cWhhL, 196608LL, comb_bih, comb_bhh,
                pH, pL, (long long)NROWS * H,
                qH, qL, (long long)NROWS * H, H, 0);
            k_fv_acc_mf<<<dim3(4, 40, 1), blk, 0, stream>>>(
                fv, qH, qL, cnH, cnL, s * 512, (4 - s) * 512 + 256);
            u16* t1 = pH; pH = qH; qH = t1;
            u16* t2 = pL; pL = qL; qL = t2;
        }
    }

    // -------- CSR build --------
    int* cnt = (int*)hBL;
    int* rowptr = cnt + 10016;
    int* cursor = rowptr + 10016;
    int* csr = cursor + 10016;
    float* dinv = (float*)(csr + NE);
    hipMemsetAsync(cnt, 0, NROWS * sizeof(int), stream);
    hipMemsetAsync(cursor, 0, NROWS * sizeof(int), stream);
    k_cnt<<<(NE + 255) / 256, blk, 0, stream>>>(cnt, edge + NE);
    k_scan<<<1, blk, 0, stream>>>(cnt, rowptr);
    k_dinv<<<(NROWS + 255) / 256, blk, 0, stream>>>(dinv, cnt);
    k_fill<<<(NE + 255) / 256, blk, 0, stream>>>(csr, cursor, rowptr, edge);

    // -------- 4 conv applications (last two share W2,b2) --------
    {
        u16* xcH = hBH;
        u16* xcL = hBH + NH;
        float* xw = (float*)hAH;
        float* xb = (float*)hAL;
        float* cur = fv;
        float* nxt = xb;
        k_split<<<(NROWS * H + 255) / 256, blk, 0, stream>>>(fv, xcH, xcL, NROWS * H);
        for (int i = 0; i < 4; ++i) {
            int wi = (i < 3) ? i : 2;
            k_gcn_gemm<<<dim3(4, 40, 1), blk, 0, stream>>>(xw, xcH, xcL,
                                                           gcH + wi * 65536, gcL + wi * 65536);
            k_gather<<<(NROWS + 3) / 4, blk, 0, stream>>>(nxt, xcH, xcL, xw, dinv, rowptr, csr,
                                                          gcn_b + wi * H);
            float* tmp = cur; cur = nxt; nxt = tmp;
        }
        k_colmax<<<256, blk, 0, stream>>>((float*)d_out, cur);
    }
}

// Round 5
// 5196.609 us; speedup vs baseline: 4.0332x; 1.0973x over previous
//
#include <hip/hip_runtime.h>
#include <math.h>

#define H 256
#define NROWS 10000
#define LTREE 8
#define TSEQ 16
#define FDIM 128
#define NE 160000

typedef __attribute__((ext_vector_type(8))) short short8;
typedef __attribute__((ext_vector_type(4))) float f32x4;
typedef unsigned short u16;

__device__ __forceinline__ u16 f2bf(float x) {
    unsigned int u = __float_as_uint(x);
    return (u16)((u + 0x7fffu + ((u >> 16) & 1u)) >> 16);
}
__device__ __forceinline__ float bf2f(u16 s) { return __uint_as_float(((unsigned int)s) << 16); }
__device__ __forceinline__ short8 ldf(const u16* __restrict__ p) { return *(const short8*)(p); }
__device__ __forceinline__ float fexp_(float x) { return __expf(fminf(x, 80.f)); }
__device__ __forceinline__ float fsig_(float x) { return 1.f / (1.f + fexp_(-x)); }
__device__ __forceinline__ float ftanh_(float x) {
    float e = fexp_(fmaxf(2.f * x, -80.f));
    return (e - 1.f) / (e + 1.f);
}
#define MFMA(A, B, C) C = __builtin_amdgcn_mfma_f32_16x16x32_bf16(A, B, C, 0, 0, 0)
#define MF3(AH, AL, BH, BL, C) do { MFMA(AH, BH, C); MFMA(AL, BH, C); MFMA(AH, BL, C); } while (0)

// XCD-aware block remap (see r3/r4): groups all col-blocks of one (y,z) on one XCD.
__device__ __forceinline__ void xcd_swz(int& cbi, int& yy, int& zz) {
    const int gx = gridDim.x, gy = gridDim.y, gz = gridDim.z;
    int bid = blockIdx.x + gx * (blockIdx.y + gy * blockIdx.z);
    int xcd = bid & 7;
    int slot = bid >> 3;
    int gpx = (gy * gz) >> 3;
    int grp = xcd * gpx + slot / gx;
    cbi = slot % gx;
    zz = grp / gy;
    yy = grp % gy;
}

// ---------------- paired (hi8|lo8 per 32B) split helpers ----------------
__device__ __forceinline__ void emit8(u16* __restrict__ dst, const float* v8) {
    short8 h, l;
#pragma unroll
    for (int j = 0; j < 8; j++) {
        u16 hh = f2bf(v8[j]);
        h[j] = (short)hh;
        l[j] = (short)f2bf(v8[j] - bf2f(hh));
    }
    *(short8*)dst = h;
    *(short8*)(dst + 8) = l;
}
__global__ void k_splitW(const float* __restrict__ src, u16* __restrict__ dst, int ngroups) {
    int g = blockIdx.x * 256 + threadIdx.x;
    if (g < ngroups) {
        float v[8];
        *(float4*)v = *(const float4*)(src + (size_t)g * 8);
        *(float4*)(v + 4) = *(const float4*)(src + (size_t)g * 8 + 4);
        emit8(dst + (size_t)g * 16, v);
    }
}
// x slice of the 4 sequences at step t -> paired [4][NROWS][128]; XCD-matched: xcd = z*2+half
__global__ void k_split_xseq(const float* __restrict__ s2, const float* __restrict__ s3,
                             const float* __restrict__ s4, const float* __restrict__ s5,
                             int t, u16* __restrict__ dst) {
    int bid = blockIdx.x;                 // 2560
    int xcd = bid & 7, chunk = bid >> 3;  // chunk 0..319
    int z = xcd >> 1, half = xcd & 1;
    int g = chunk * 256 + threadIdx.x;    // 0..81919
    int row = half * 5120 + (g >> 4);
    if (row >= NROWS) return;
    int col = (g & 15) * 8;
    const float* s = (z == 0) ? s2 : (z == 1) ? s3 : (z == 2) ? s4 : s5;
    const float* p = s + (size_t)row * (TSEQ * FDIM) + t * FDIM + col;
    float v[8];
    *(float4*)v = *(const float4*)p;
    *(float4*)(v + 4) = *(const float4*)(p + 4);
    emit8(dst + (size_t)z * 2560000 + (size_t)row * 256 + (size_t)(g & 15) * 16, v);
}
// tree x slice at step t -> paired [NROWS][128]; XCD-matched: xcd = row/1280
__global__ void k_split_xtree(const float* __restrict__ tree, int t, u16* __restrict__ dst) {
    int bid = blockIdx.x;                 // 640
    int xcd = bid & 7, chunk = bid >> 3;  // 0..79
    int g = chunk * 256 + threadIdx.x;    // 0..20479
    int row = xcd * 1280 + (g >> 4);
    if (row >= NROWS) return;
    int col = (g & 15) * 8;
    const float* p = tree + (size_t)row * (LTREE * FDIM) + t * FDIM + col;
    float v[8];
    *(float4*)v = *(const float4*)p;
    *(float4*)(v + 4) = *(const float4*)(p + 4);
    emit8(dst + (size_t)row * 256 + (size_t)(g & 15) * 16, v);
}
// flat [NROWS][256] f32 -> paired
__global__ void k_splitNH(const float* __restrict__ src, u16* __restrict__ dst) {
    int g = blockIdx.x * 256 + threadIdx.x;  // 320000 groups
    if (g < NROWS * 32) {
        float v[8];
        *(float4*)v = *(const float4*)(src + (size_t)g * 8);
        *(float4*)(v + 4) = *(const float4*)(src + (size_t)g * 8 + 4);
        emit8(dst + (size_t)g * 16, v);
    }
}

// ---------------------------------------------------------------------------
// GRU step: paired operands, imm-offset loads, unrolled, XCD-swizzled.
// All strides in u16 units. Wih/Whh paired row stride = K*2.
// ---------------------------------------------------------------------------
template <int KX>
__global__ __launch_bounds__(256) void k_rnn_step(
    const u16* __restrict__ xp, long long xzs, int xld2, int xc0, int xc1,
    const u16* __restrict__ Wih, long long wz,
    const u16* __restrict__ Whh, long long wzh,
    const float* __restrict__ bihB, const float* __restrict__ bhhB,
    const u16* __restrict__ hp, long long hz,
    u16* __restrict__ op, long long ozs, int oldv2, int ocoff) {
    const int tid = threadIdx.x, lane = tid & 63, w = tid >> 6;
    const int lx = lane & 15, kl = (lane >> 4) * 8;
    int cbi, yy, z;
    xcd_swz(cbi, yy, z);
    const int cb = cbi * 16, m0 = yy * 256 + w * 64;
    int arow[4];
#pragma unroll
    for (int rf = 0; rf < 4; rf++) {
        int r = m0 + rf * 16 + lx;
        arow[rf] = (r < NROWS) ? r : NROWS - 1;
    }
    const u16* xb = xp + (size_t)z * xzs + (size_t)((z == 1) ? xc1 : xc0) * 2;
    const u16* Wihz = Wih + (size_t)z * wz;
    const u16* Whhz = Whh + (size_t)z * wzh;
    const u16* hpz = hp + (size_t)z * hz;
    const float* bih = bihB + z * 768;
    const float* bhh = bhhB + z * 768;

    const f32x4 zf = {0.f, 0.f, 0.f, 0.f};
    f32x4 aR[4] = {zf, zf, zf, zf}, aZ[4] = {zf, zf, zf, zf};
    f32x4 aNX[4] = {zf, zf, zf, zf}, aNH[4] = {zf, zf, zf, zf};

    {
        const u16* ax0 = xb + (size_t)arow[0] * xld2 + kl * 2;
        const u16* ax1 = xb + (size_t)arow[1] * xld2 + kl * 2;
        const u16* ax2 = xb + (size_t)arow[2] * xld2 + kl * 2;
        const u16* ax3 = xb + (size_t)arow[3] * xld2 + kl * 2;
        const u16* bx0 = Wihz + (size_t)(cb + lx) * (KX * 2) + kl * 2;
        const u16* bx1 = bx0 + 256 * KX * 2;
        const u16* bx2 = bx0 + 512 * KX * 2;
#pragma unroll
        for (int kb = 0; kb < KX; kb += 32) {
            short8 axh[4], axl[4];
            axh[0] = ldf(ax0 + kb * 2); axl[0] = ldf(ax0 + kb * 2 + 8);
            axh[1] = ldf(ax1 + kb * 2); axl[1] = ldf(ax1 + kb * 2 + 8);
            axh[2] = ldf(ax2 + kb * 2); axl[2] = ldf(ax2 + kb * 2 + 8);
            axh[3] = ldf(ax3 + kb * 2); axl[3] = ldf(ax3 + kb * 2 + 8);
            {
                short8 bh = ldf(bx0 + kb * 2), bl = ldf(bx0 + kb * 2 + 8);
#pragma unroll
                for (int rf = 0; rf < 4; rf++) MF3(axh[rf], axl[rf], bh, bl, aR[rf]);
            }
            {
                short8 bh = ldf(bx1 + kb * 2), bl = ldf(bx1 + kb * 2 + 8);
#pragma unroll
                for (int rf = 0; rf < 4; rf++) MF3(axh[rf], axl[rf], bh, bl, aZ[rf]);
            }
            {
                short8 bh = ldf(bx2 + kb * 2), bl = ldf(bx2 + kb * 2 + 8);
#pragma unroll
                for (int rf = 0; rf < 4; rf++) MF3(axh[rf], axl[rf], bh, bl, aNX[rf]);
            }
        }
    }
    {
        const u16* ah0 = hpz + (size_t)arow[0] * 512 + kl * 2;
        const u16* ah1 = hpz + (size_t)arow[1] * 512 + kl * 2;
        const u16* ah2 = hpz + (size_t)arow[2] * 512 + kl * 2;
        const u16* ah3 = hpz + (size_t)arow[3] * 512 + kl * 2;
        const u16* bh0 = Whhz + (size_t)(cb + lx) * 512 + kl * 2;
        const u16* bh1 = bh0 + 131072;
        const u16* bh2 = bh0 + 262144;
#pragma unroll
        for (int kb = 0; kb < 256; kb += 32) {
            short8 axh[4], axl[4];
            axh[0] = ldf(ah0 + kb * 2); axl[0] = ldf(ah0 + kb * 2 + 8);
            axh[1] = ldf(ah1 + kb * 2); axl[1] = ldf(ah1 + kb * 2 + 8);
            axh[2] = ldf(ah2 + kb * 2); axl[2] = ldf(ah2 + kb * 2 + 8);
            axh[3] = ldf(ah3 + kb * 2); axl[3] = ldf(ah3 + kb * 2 + 8);
            {
                short8 bh = ldf(bh0 + kb * 2), bl = ldf(bh0 + kb * 2 + 8);
#pragma unroll
                for (int rf = 0; rf < 4; rf++) MF3(axh[rf], axl[rf], bh, bl, aR[rf]);
            }
            {
                short8 bh = ldf(bh1 + kb * 2), bl = ldf(bh1 + kb * 2 + 8);
#pragma unroll
                for (int rf = 0; rf < 4; rf++) MF3(axh[rf], axl[rf], bh, bl, aZ[rf]);
            }
            {
                short8 bh = ldf(bh2 + kb * 2), bl = ldf(bh2 + kb * 2 + 8);
#pragma unroll
                for (int rf = 0; rf < 4; rf++) MF3(axh[rf], axl[rf], bh, bl, aNH[rf]);
            }
        }
    }
    const int col = cb + lx;
    const float b_r = bih[col] + bhh[col];
    const float b_z = bih[256 + col] + bhh[256 + col];
    const float bx_n = bih[512 + col], bh_n = bhh[512 + col];
    const int cpo = ((col >> 3) << 4) + (col & 7);
    u16* ob = op + (size_t)z * ozs + (size_t)ocoff * 2;
#pragma unroll
    for (int rf = 0; rf < 4; rf++) {
#pragma unroll
        for (int rr = 0; rr < 4; rr++) {
            int row = m0 + rf * 16 + (lane >> 4) * 4 + rr;
            if (row < NROWS) {
                float rg = fsig_(aR[rf][rr] + b_r);
                float zg = fsig_(aZ[rf][rr] + b_z);
                float ng = ftanh_(aNX[rf][rr] + bx_n + rg * (aNH[rf][rr] + bh_n));
                size_t hidx = (size_t)row * 512 + cpo;
                float hold = bf2f(hpz[hidx]) + bf2f(hpz[hidx + 8]);
                float hnew = (1.f - zg) * ng + zg * hold;
                size_t oi = (size_t)row * oldv2 + cpo;
                u16 hh = f2bf(hnew);
                ob[oi] = hh;
                ob[oi + 8] = f2bf(hnew - bf2f(hh));
            }
        }
    }
}

// ---------------------------------------------------------------------------
// TreeLSTM step (chain): 4 classes both phases, c f32 in-place.
// ---------------------------------------------------------------------------
__global__ __launch_bounds__(256) void k_tree_step_mf(
    const u16* __restrict__ txp,
    const u16* __restrict__ Wx, const u16* __restrict__ Wh,
    const u16* __restrict__ Wfx, const u16* __restrict__ Wfh,
    const float* __restrict__ bioux, const float* __restrict__ biouh,
    const float* __restrict__ bfx, const float* __restrict__ bfh,
    const u16* __restrict__ hp, float* __restrict__ cst,
    u16* __restrict__ op, int oldv2) {
    const int tid = threadIdx.x, lane = tid & 63, w = tid >> 6;
    const int lx = lane & 15, kl = (lane >> 4) * 8;
    int cbi, yy, zz;
    xcd_swz(cbi, yy, zz);
    const int cb = cbi * 16, m0 = yy * 256 + w * 64;
    int arow[4];
#pragma unroll
    for (int rf = 0; rf < 4; rf++) {
        int r = m0 + rf * 16 + lx;
        arow[rf] = (r < NROWS) ? r : NROWS - 1;
    }
    const f32x4 zf = {0.f, 0.f, 0.f, 0.f};
    f32x4 aI[4] = {zf, zf, zf, zf}, aO[4] = {zf, zf, zf, zf};
    f32x4 aU[4] = {zf, zf, zf, zf}, aF[4] = {zf, zf, zf, zf};
    {
        const u16* ax0 = txp + (size_t)arow[0] * 256 + kl * 2;
        const u16* ax1 = txp + (size_t)arow[1] * 256 + kl * 2;
        const u16* ax2 = txp + (size_t)arow[2] * 256 + kl * 2;
        const u16* ax3 = txp + (size_t)arow[3] * 256 + kl * 2;
        const u16* bx0 = Wx + (size_t)(cb + lx) * 256 + kl * 2;
        const u16* bx1 = bx0 + 65536;
        const u16* bx2 = bx0 + 131072;
        const u16* bf0 = Wfx + (size_t)(cb + lx) * 256 + kl * 2;
#pragma unroll
        for (int kb = 0; kb < 128; kb += 32) {
            short8 axh[4], axl[4];
            axh[0] = ldf(ax0 + kb * 2); axl[0] = ldf(ax0 + kb * 2 + 8);
            axh[1] = ldf(ax1 + kb * 2); axl[1] = ldf(ax1 + kb * 2 + 8);
            axh[2] = ldf(ax2 + kb * 2); axl[2] = ldf(ax2 + kb * 2 + 8);
            axh[3] = ldf(ax3 + kb * 2); axl[3] = ldf(ax3 + kb * 2 + 8);
            {
                short8 bh = ldf(bx0 + kb * 2), bl = ldf(bx0 + kb * 2 + 8);
#pragma unroll
                for (int rf = 0; rf < 4; rf++) MF3(axh[rf], axl[rf], bh, bl, aI[rf]);
            }
            {
                short8 bh = ldf(bx1 + kb * 2), bl = ldf(bx1 + kb * 2 + 8);
#pragma unroll
                for (int rf = 0; rf < 4; rf++) MF3(axh[rf], axl[rf], bh, bl, aO[rf]);
            }
            {
                short8 bh = ldf(bx2 + kb * 2), bl = ldf(bx2 + kb * 2 + 8);
#pragma unroll
                for (int rf = 0; rf < 4; rf++) MF3(axh[rf], axl[rf], bh, bl, aU[rf]);
            }
            {
                short8 bh = ldf(bf0 + kb * 2), bl = ldf(bf0 + kb * 2 + 8);
#pragma unroll
                for (int rf = 0; rf < 4; rf++) MF3(axh[rf], axl[rf], bh, bl, aF[rf]);
            }
        }
    }
    {
        const u16* ah0 = hp + (size_t)arow[0] * 512 + kl * 2;
        const u16* ah1 = hp + (size_t)arow[1] * 512 + kl * 2;
        const u16* ah2 = hp + (size_t)arow[2] * 512 + kl * 2;
        const u16* ah3 = hp + (size_t)arow[3] * 512 + kl * 2;
        const u16* bh0 = Wh + (size_t)(cb + lx) * 512 + kl * 2;
        const u16* bh1 = bh0 + 131072;
        const u16* bh2 = bh0 + 262144;
        const u16* bf0 = Wfh + (size_t)(cb + lx) * 512 + kl * 2;
#pragma unroll
        for (int kb = 0; kb < 256; kb += 32) {
            short8 axh[4], axl[4];
            axh[0] = ldf(ah0 + kb * 2); axl[0] = ldf(ah0 + kb * 2 + 8);
            axh[1] = ldf(ah1 + kb * 2); axl[1] = ldf(ah1 + kb * 2 + 8);
            axh[2] = ldf(ah2 + kb * 2); axl[2] = ldf(ah2 + kb * 2 + 8);
            axh[3] = ldf(ah3 + kb * 2); axl[3] = ldf(ah3 + kb * 2 + 8);
            {
                short8 bh = ldf(bh0 + kb * 2), bl = ldf(bh0 + kb * 2 + 8);
#pragma unroll
                for (int rf = 0; rf < 4; rf++) MF3(axh[rf], axl[rf], bh, bl, aI[rf]);
            }
            {
                short8 bh = ldf(bh1 + kb * 2), bl = ldf(bh1 + kb * 2 + 8);
#pragma unroll
                for (int rf = 0; rf < 4; rf++) MF3(axh[rf], axl[rf], bh, bl, aO[rf]);
            }
            {
                short8 bh = ldf(bh2 + kb * 2), bl = ldf(bh2 + kb * 2 + 8);
#pragma unroll
                for (int rf = 0; rf < 4; rf++) MF3(axh[rf], axl[rf], bh, bl, aU[rf]);
            }
            {
                short8 bh = ldf(bf0 + kb * 2), bl = ldf(bf0 + kb * 2 + 8);
#pragma unroll
                for (int rf = 0; rf < 4; rf++) MF3(axh[rf], axl[rf], bh, bl, aF[rf]);
            }
        }
    }
    const int col = cb + lx;
    const float b_i = bioux[col] + biouh[col];
    const float b_o = bioux[256 + col] + biouh[256 + col];
    const float b_u = bioux[512 + col] + biouh[512 + col];
    const float b_f = bfx[col] + bfh[col];
    const int cpo = ((col >> 3) << 4) + (col & 7);
#pragma unroll
    for (int rf = 0; rf < 4; rf++) {
#pragma unroll
        for (int rr = 0; rr < 4; rr++) {
            int row = m0 + rf * 16 + (lane >> 4) * 4 + rr;
            if (row < NROWS) {
                float ig = fsig_(aI[rf][rr] + b_i);
                float og = fsig_(aO[rf][rr] + b_o);
                float ug = ftanh_(aU[rf][rr] + b_u);
                float fg = fsig_(aF[rf][rr] + b_f);
                size_t ci = (size_t)row * H + col;
                float cnew = ig * ug + fg * cst[ci];
                cst[ci] = cnew;
                float hnew = og * ftanh_(cnew);
                size_t oi = (size_t)row * oldv2 + cpo;
                u16 hh = f2bf(hnew);
                op[oi] = hh;
                op[oi + 8] = f2bf(hnew - bf2f(hh));
            }
        }
    }
}

// fv += hf @ Wc[:,off_f:+256]^T + hb @ Wc[:,off_b:+256]^T (paired, wave 64x64)
__global__ __launch_bounds__(256) void k_fv_acc_mf(
    float* __restrict__ fv, const u16* __restrict__ hq,
    const u16* __restrict__ Wc, int off_f, int off_b) {
    const int tid = threadIdx.x, lane = tid & 63, w = tid >> 6;
    const int lx = lane & 15, kl = (lane >> 4) * 8;
    int cbi, yy, zz;
    xcd_swz(cbi, yy, zz);
    const int cb = cbi * 64, m0 = yy * 256 + w * 64;
    int arow[4];
#pragma unroll
    for (int rf = 0; rf < 4; rf++) {
        int r = m0 + rf * 16 + lx;
        arow[rf] = (r < NROWS) ? r : NROWS - 1;
    }
    const f32x4 zf = {0.f, 0.f, 0.f, 0.f};
    f32x4 acc[4][4] = {{zf, zf, zf, zf}, {zf, zf, zf, zf}, {zf, zf, zf, zf}, {zf, zf, zf, zf}};
    for (int ph = 0; ph < 2; ph++) {
        const u16* aB = hq + (size_t)ph * 5120000;
        const int off = ph ? off_b : off_f;
        const u16* a0 = aB + (size_t)arow[0] * 512 + kl * 2;
        const u16* a1 = aB + (size_t)arow[1] * 512 + kl * 2;
        const u16* a2 = aB + (size_t)arow[2] * 512 + kl * 2;
        const u16* a3 = aB + (size_t)arow[3] * 512 + kl * 2;
        const u16* bp0 = Wc + (size_t)(cb + lx) * 5120 + (size_t)off * 2 + kl * 2;
        const u16* bp1 = bp0 + 16 * 5120;
        const u16* bp2 = bp0 + 32 * 5120;
        const u16* bp3 = bp0 + 48 * 5120;
#pragma unroll
        for (int kb = 0; kb < 256; kb += 32) {
            short8 axh[4], axl[4];
            axh[0] = ldf(a0 + kb * 2); axl[0] = ldf(a0 + kb * 2 + 8);
            axh[1] = ldf(a1 + kb * 2); axl[1] = ldf(a1 + kb * 2 + 8);
            axh[2] = ldf(a2 + kb * 2); axl[2] = ldf(a2 + kb * 2 + 8);
            axh[3] = ldf(a3 + kb * 2); axl[3] = ldf(a3 + kb * 2 + 8);
            {
                short8 bh = ldf(bp0 + kb * 2), bl = ldf(bp0 + kb * 2 + 8);
#pragma unroll
                for (int rf = 0; rf < 4; rf++) MF3(axh[rf], axl[rf], bh, bl, acc[rf][0]);
            }
            {
                short8 bh = ldf(bp1 + kb * 2), bl = ldf(bp1 + kb * 2 + 8);
#pragma unroll
                for (int rf = 0; rf < 4; rf++) MF3(axh[rf], axl[rf], bh, bl, acc[rf][1]);
            }
            {
                short8 bh = ldf(bp2 + kb * 2), bl = ldf(bp2 + kb * 2 + 8);
#pragma unroll
                for (int rf = 0; rf < 4; rf++) MF3(axh[rf], axl[rf], bh, bl, acc[rf][2]);
            }
            {
                short8 bh = ldf(bp3 + kb * 2), bl = ldf(bp3 + kb * 2 + 8);
#pragma unroll
                for (int rf = 0; rf < 4; rf++) MF3(axh[rf], axl[rf], bh, bl, acc[rf][3]);
            }
        }
    }
#pragma unroll
    for (int rf = 0; rf < 4; rf++) {
#pragma unroll
        for (int cf = 0; cf < 4; cf++) {
            int col = cb + cf * 16 + lx;
#pragma unroll
            for (int rr = 0; rr < 4; rr++) {
                int row = m0 + rf * 16 + (lane >> 4) * 4 + rr;
                if (row < NROWS) fv[(size_t)row * H + col] += acc[rf][cf][rr];
            }
        }
    }
}

// out = A @ W^T  (A paired [N,512u16], W paired [256][512u16])
__global__ __launch_bounds__(256) void k_gcn_gemm(
    float* __restrict__ out, const u16* __restrict__ ap_, const u16* __restrict__ W) {
    const int tid = threadIdx.x, lane = tid & 63, w = tid >> 6;
    const int lx = lane & 15, kl = (lane >> 4) * 8;
    int cbi, yy, zz;
    xcd_swz(cbi, yy, zz);
    const int cb = cbi * 64, m0 = yy * 256 + w * 64;
    int arow[4];
#pragma unroll
    for (int rf = 0; rf < 4; rf++) {
        int r = m0 + rf * 16 + lx;
        arow[rf] = (r < NROWS) ? r : NROWS - 1;
    }
    const f32x4 zf = {0.f, 0.f, 0.f, 0.f};
    f32x4 acc[4][4] = {{zf, zf, zf, zf}, {zf, zf, zf, zf}, {zf, zf, zf, zf}, {zf, zf, zf, zf}};
    const u16* a0 = ap_ + (size_t)arow[0] * 512 + kl * 2;
    const u16* a1 = ap_ + (size_t)arow[1] * 512 + kl * 2;
    const u16* a2 = ap_ + (size_t)arow[2] * 512 + kl * 2;
    const u16* a3 = ap_ + (size_t)arow[3] * 512 + kl * 2;
    const u16* bp0 = W + (size_t)(cb + lx) * 512 + kl * 2;
    const u16* bp1 = bp0 + 16 * 512;
    const u16* bp2 = bp0 + 32 * 512;
    const u16* bp3 = bp0 + 48 * 512;
#pragma unroll
    for (int kb = 0; kb < 256; kb += 32) {
        short8 axh[4], axl[4];
        axh[0] = ldf(a0 + kb * 2); axl[0] = ldf(a0 + kb * 2 + 8);
        axh[1] = ldf(a1 + kb * 2); axl[1] = ldf(a1 + kb * 2 + 8);
        axh[2] = ldf(a2 + kb * 2); axl[2] = ldf(a2 + kb * 2 + 8);
        axh[3] = ldf(a3 + kb * 2); axl[3] = ldf(a3 + kb * 2 + 8);
        {
            short8 bh = ldf(bp0 + kb * 2), bl = ldf(bp0 + kb * 2 + 8);
#pragma unroll
            for (int rf = 0; rf < 4; rf++) MF3(axh[rf], axl[rf], bh, bl, acc[rf][0]);
        }
        {
            short8 bh = ldf(bp1 + kb * 2), bl = ldf(bp1 + kb * 2 + 8);
#pragma unroll
            for (int rf = 0; rf < 4; rf++) MF3(axh[rf], axl[rf], bh, bl, acc[rf][1]);
        }
        {
            short8 bh = ldf(bp2 + kb * 2), bl = ldf(bp2 + kb * 2 + 8);
#pragma unroll
            for (int rf = 0; rf < 4; rf++) MF3(axh[rf], axl[rf], bh, bl, acc[rf][2]);
        }
        {
            short8 bh = ldf(bp3 + kb * 2), bl = ldf(bp3 + kb * 2 + 8);
#pragma unroll
            for (int rf = 0; rf < 4; rf++) MF3(axh[rf], axl[rf], bh, bl, acc[rf][3]);
        }
    }
#pragma unroll
    for (int rf = 0; rf < 4; rf++) {
#pragma unroll
        for (int cf = 0; cf < 4; cf++) {
            int col = cb + cf * 16 + lx;
#pragma unroll
            for (int rr = 0; rr < 4; rr++) {
                int row = m0 + rf * 16 + (lane >> 4) * 4 + rr;
                if (row < NROWS) out[(size_t)row * H + col] = acc[rf][cf][rr];
            }
        }
    }
}

// ---------------------------- GCN small kernels -----------------------------
__global__ void k_fv_init(float* fv, const float* __restrict__ b) {
    int idx = blockIdx.x * 256 + threadIdx.x;
    if (idx < NROWS * H) fv[idx] = b[idx & (H - 1)];
}
__global__ void k_cnt(int* __restrict__ cnt, const int* __restrict__ dst) {
    int i = blockIdx.x * 256 + threadIdx.x;
    if (i < NE) atomicAdd(&cnt[dst[i]], 1);
}
__global__ void k_scan(const int* __restrict__ cnt, int* __restrict__ rowptr) {
    __shared__ int part[256];
    int tid = threadIdx.x;
    int st = tid * 40, en = (st + 40 > NROWS) ? NROWS : st + 40;
    int s = 0;
    for (int i = st; i < en; i++) s += cnt[i];
    part[tid] = s;
    __syncthreads();
    if (tid == 0) {
        int run = 0;
        for (int i = 0; i < 256; i++) { int t = part[i]; part[i] = run; run += t; }
        rowptr[NROWS] = run;
    }
    __syncthreads();
    int run = part[tid];
    for (int i = st; i < en; i++) { rowptr[i] = run; run += cnt[i]; }
}
__global__ void k_dinv(float* __restrict__ dinv, const int* __restrict__ cnt) {
    int i = blockIdx.x * 256 + threadIdx.x;
    if (i < NROWS) dinv[i] = rsqrtf(1.0f + (float)cnt[i]);
}
__global__ void k_fill(int* __restrict__ csr, int* __restrict__ cursor,
                       const int* __restrict__ rowptr, const int* __restrict__ ei) {
    int e = blockIdx.x * 256 + threadIdx.x;
    if (e < NE) {
        int d = ei[NE + e];
        int p = atomicAdd(&cursor[d], 1);
        csr[rowptr[d] + p] = ei[e];
    }
}
// out[node] = relu(norm-agg + b); also emits paired bf16 split for the next conv
__global__ __launch_bounds__(256) void k_gather(
    float* __restrict__ out, u16* __restrict__ xcp,
    const float* __restrict__ xw, const float* __restrict__ dinv,
    const int* __restrict__ rowptr, const int* __restrict__ csr, const float* __restrict__ b) {
    int node = blockIdx.x * 4 + (threadIdx.x >> 6);
    if (node >= NROWS) return;
    int lane = threadIdx.x & 63;
    float dn = dinv[node];
    float4 acc = *(const float4*)(xw + (size_t)node * H + lane * 4);
    float dn2 = dn * dn;
    acc.x *= dn2; acc.y *= dn2; acc.z *= dn2; acc.w *= dn2;
    int e0 = rowptr[node], e1 = rowptr[node + 1];
    for (int i = e0; i < e1; i++) {
        int s = csr[i];
        float wgt = dn * dinv[s];
        const float4 v = *(const float4*)(xw + (size_t)s * H + lane * 4);
        acc.x += v.x * wgt; acc.y += v.y * wgt; acc.z += v.z * wgt; acc.w += v.w * wgt;
    }
    const float4 bv = *(const float4*)(b + lane * 4);
    float o[4];
    o[0] = fmaxf(acc.x + bv.x, 0.f);
    o[1] = fmaxf(acc.y + bv.y, 0.f);
    o[2] = fmaxf(acc.z + bv.z, 0.f);
    o[3] = fmaxf(acc.w + bv.w, 0.f);
    *(float4*)(out + (size_t)node * H + lane * 4) = *(const float4*)o;
    u16 hs[4], ls[4];
#pragma unroll
    for (int j = 0; j < 4; j++) {
        hs[j] = f2bf(o[j]);
        ls[j] = f2bf(o[j] - bf2f(hs[j]));
    }
    size_t bidx = (size_t)node * 512 + (size_t)(lane >> 1) * 16 + (lane & 1) * 4;
    *(short4*)(xcp + bidx) = *(const short4*)hs;
    *(short4*)(xcp + bidx + 8) = *(const short4*)ls;
}
__global__ void k_colmax(float* __restrict__ out, const float* __restrict__ x) {
    int j = threadIdx.x;
    float m = 0.0f;
    for (int r = blockIdx.x; r < NROWS; r += gridDim.x)
        m = fmaxf(m, x[(size_t)r * H + j]);
    atomicMax((int*)&out[j], __float_as_int(m));
}

// ---------------------------------------------------------------------------
extern "C" void kernel_launch(void* const* d_in, const int* in_sizes, int n_in,
                              void* d_out, int out_size, void* d_ws, size_t ws_size,
                              hipStream_t stream) {
    const float* tree = (const float*)d_in[0];
    const float* s2 = (const float*)d_in[1];
    const float* s3 = (const float*)d_in[2];
    const float* s4 = (const float*)d_in[3];
    const float* s5 = (const float*)d_in[4];
    const int* edge = (const int*)d_in[5];
    const float* tl_Wioux = (const float*)d_in[6];
    const float* tl_bioux = (const float*)d_in[7];
    const float* tl_Wiouh = (const float*)d_in[8];
    const float* tl_biouh = (const float*)d_in[9];
    const float* tl_Wfx = (const float*)d_in[10];
    const float* tl_bfx = (const float*)d_in[11];
    const float* tl_Wfh = (const float*)d_in[12];
    const float* tl_bfh = (const float*)d_in[13];
    const float* gru_Wih = (const float*)d_in[14];
    const float* gru_Whh = (const float*)d_in[15];
    const float* gru_bih = (const float*)d_in[16];
    const float* gru_bhh = (const float*)d_in[17];
    const float* comb_Wih = (const float*)d_in[18];
    const float* comb_Whh = (const float*)d_in[19];
    const float* comb_bih = (const float*)d_in[20];
    const float* comb_bhh = (const float*)d_in[21];
    const float* connect_W = (const float*)d_in[22];
    const float* connect_b = (const float*)d_in[23];
    const float* gcn_W = (const float*)d_in[24];
    const float* gcn_b = (const float*)d_in[25];

    char* base = (char*)d_ws;
    size_t off = 0;
    auto aus = [&](size_t nu16) { u16* p = (u16*)(base + off); off += nu16 * sizeof(u16); return p; };
    // paired weights (u16 count = 2 * element count)
    u16* tx = aus(196608);
    u16* th = aus(393216);
    u16* tfx = aus(65536);
    u16* tfh = aus(131072);
    u16* gWih = aus(786432);
    u16* gWhh = aus(1572864);
    u16* cWih = aus(786432);
    u16* cWhh = aus(786432);
    u16* cn = aus(1310720);
    u16* gc = aus(393216);
    u16* feats = aus((size_t)NROWS * 2560);   // [10000][1280] paired
    u16* hA = aus((size_t)4 * NROWS * 512);   // up to 4 z
    u16* hB = aus((size_t)4 * NROWS * 512);
    u16* SA = aus((size_t)10240000);          // 20.48 MB scratch

    const dim3 blk(256);

    hipMemsetAsync(d_out, 0, H * sizeof(float), stream);

    // -------- split weights to paired bf16 hi/lo --------
    auto SPW = [&](const float* s, u16* d, int n) {
        k_splitW<<<(n / 8 + 255) / 256, blk, 0, stream>>>(s, d, n / 8);
    };
    SPW(tl_Wioux, tx, 98304);
    SPW(tl_Wiouh, th, 196608);
    SPW(tl_Wfx, tfx, 32768);
    SPW(tl_Wfh, tfh, 65536);
    SPW(gru_Wih, gWih, 393216);
    SPW(gru_Whh, gWhh, 786432);
    SPW(comb_Wih, cWih, 393216);
    SPW(comb_Whh, cWhh, 393216);
    SPW(connect_W, cn, 655360);
    SPW(gcn_W, gc, 196608);

    // -------- TreeLSTM (8 steps) --------
    float* cbuf = (float*)SA;                 // 10.24 MB
    u16* xtree = SA + 5120000;                // 5.12 MB paired x slice
    hipMemsetAsync(hA, 0, (size_t)NROWS * 512 * 2, stream);
    hipMemsetAsync(cbuf, 0, (size_t)NROWS * H * 4, stream);
    {
        u16 *p = hA, *q = hB;
        for (int t = 0; t < LTREE; ++t) {
            bool last = (t == LTREE - 1);
            k_split_xtree<<<640, blk, 0, stream>>>(tree, t, xtree);
            k_tree_step_mf<<<dim3(16, 40, 1), blk, 0, stream>>>(
                xtree, tx, th, tfx, tfh, tl_bioux, tl_biouh, tl_bfx, tl_bfh,
                p, cbuf, last ? feats : q, last ? 2560 : 512);
            u16* tmp = p; p = q; q = tmp;
        }
    }

    // -------- 4 GRUs (16 steps, z=4) --------
    u16* xs = SA;  // [4][10000][256 u16] = 10.24M u16
    hipMemsetAsync(hA, 0, (size_t)4 * NROWS * 512 * 2, stream);
    {
        u16 *p = hA, *q = hB;
        for (int t = 0; t < TSEQ; ++t) {
            bool last = (t == TSEQ - 1);
            k_split_xseq<<<2560, blk, 0, stream>>>(s2, s3, s4, s5, t, xs);
            k_rnn_step<128><<<dim3(16, 40, 4), blk, 0, stream>>>(
                xs, 2560000LL, 256, 0, 0,
                gWih, 196608LL, gWhh, 393216LL, gru_bih, gru_bhh,
                p, (long long)NROWS * 512,
                last ? feats + 512 : q, last ? 512LL : (long long)NROWS * 512,
                last ? 2560 : 512, 0);
            u16* tmp = p; p = q; q = tmp;
        }
    }

    // -------- combine bi-GRU (5 steps, z=2) + fused connect --------
    float* fv = (float*)SA;  // xs dead now
    hipMemsetAsync(hA, 0, (size_t)2 * NROWS * 512 * 2, stream);
    k_fv_init<<<(NROWS * H + 255) / 256, blk, 0, stream>>>(fv, connect_b);
    {
        u16 *p = hA, *q = hB;
        for (int s = 0; s < 5; ++s) {
            k_rnn_step<256><<<dim3(16, 40, 2), blk, 0, stream>>>(
                feats, 0LL, 2560, s * 256, (4 - s) * 256,
                cWih, 393216LL, cWhh, 393216LL, comb_bih, comb_bhh,
                p, (long long)NROWS * 512,
                q, (long long)NROWS * 512, 512, 0);
            k_fv_acc_mf<<<dim3(4, 40, 1), blk, 0, stream>>>(
                fv, q, cn, s * 512, (4 - s) * 512 + 256);
            u16* tmp = p; p = q; q = tmp;
        }
    }

    // -------- CSR build (hB tail region) --------
    int* cnt = (int*)(hB + 6000000);
    int* rowptr = cnt + 10016;
    int* cursor = rowptr + 10016;
    int* csr = cursor + 10016;
    float* dinv = (float*)(csr + NE);
    hipMemsetAsync(cnt, 0, NROWS * sizeof(int), stream);
    hipMemsetAsync(cursor, 0, NROWS * sizeof(int), stream);
    k_cnt<<<(NE + 255) / 256, blk, 0, stream>>>(cnt, edge + NE);
    k_scan<<<1, blk, 0, stream>>>(cnt, rowptr);
    k_dinv<<<(NROWS + 255) / 256, blk, 0, stream>>>(dinv, cnt);
    k_fill<<<(NE + 255) / 256, blk, 0, stream>>>(csr, cursor, rowptr, edge);

    // -------- 4 conv applications (last two share W2,b2) --------
    {
        u16* xc = hB;                          // paired conv input
        float* xw = (float*)(SA + 5120000);    // gemm output
        float* xb = (float*)hA;
        float* cur = fv;
        float* nxt = xb;
        k_splitNH<<<1250, blk, 0, stream>>>(fv, xc);
        for (int i = 0; i < 4; ++i) {
            int wi = (i < 3) ? i : 2;
            k_gcn_gemm<<<dim3(4, 40, 1), blk, 0, stream>>>(xw, xc, gc + (size_t)wi * 131072);
            k_gather<<<(NROWS + 3) / 4, blk, 0, stream>>>(nxt, xc, xw, dinv, rowptr, csr,
                                                          gcn_b + wi * H);
            float* tmp = cur; cur = nxt; nxt = tmp;
        }
        k_colmax<<<256, blk, 0, stream>>>((float*)d_out, cur);
    }
}

// Round 6
// 4883.208 us; speedup vs baseline: 4.2921x; 1.0642x over previous
//
#include <hip/hip_runtime.h>
#include <math.h>

#define H 256
#define NROWS 10000
#define LTREE 8
#define TSEQ 16
#define FDIM 128
#define NE 160000

typedef __attribute__((ext_vector_type(8))) short short8;
typedef __attribute__((ext_vector_type(4))) float f32x4;
typedef unsigned short u16;

__device__ __forceinline__ u16 f2bf(float x) {
    unsigned int u = __float_as_uint(x);
    return (u16)((u + 0x7fffu + ((u >> 16) & 1u)) >> 16);
}
__device__ __forceinline__ float bf2f(u16 s) { return __uint_as_float(((unsigned int)s) << 16); }
__device__ __forceinline__ short8 ldf(const u16* __restrict__ p) { return *(const short8*)(p); }
__device__ __forceinline__ float fexp_(float x) { return __expf(fminf(x, 80.f)); }
__device__ __forceinline__ float fsig_(float x) { return 1.f / (1.f + fexp_(-x)); }
__device__ __forceinline__ float ftanh_(float x) {
    float e = fexp_(fmaxf(2.f * x, -80.f));
    return (e - 1.f) / (e + 1.f);
}
#define MFMA(A, B, C) C = __builtin_amdgcn_mfma_f32_16x16x32_bf16(A, B, C, 0, 0, 0)
#define MF3(AH, AL, BH, BL, C) do { MFMA(AH, BH, C); MFMA(AL, BH, C); MFMA(AH, BL, C); } while (0)

// XCD-aware remap, bijective whenever nwg%8==0: xcd gets a contiguous wgid
// chunk; decompose wgid x-major so all col-blocks of a (yy,zz) share an XCD.
__device__ __forceinline__ void xcd_swz(int& cbi, int& yy, int& zz) {
    const int gx = gridDim.x, gy = gridDim.y;
    int nwg8 = (gx * gy * gridDim.z) >> 3;
    int bid = blockIdx.x + gx * (blockIdx.y + gy * blockIdx.z);
    int wgid = (bid & 7) * nwg8 + (bid >> 3);
    cbi = wgid % gx;
    int rem = wgid / gx;
    yy = rem % gy;
    zz = rem / gy;
}

// ---------------- paired (hi8|lo8 per 32B) split helpers ----------------
__device__ __forceinline__ void emit8(u16* __restrict__ dst, const float* v8) {
    short8 h, l;
#pragma unroll
    for (int j = 0; j < 8; j++) {
        u16 hh = f2bf(v8[j]);
        h[j] = (short)hh;
        l[j] = (short)f2bf(v8[j] - bf2f(hh));
    }
    *(short8*)dst = h;
    *(short8*)(dst + 8) = l;
}
__global__ void k_splitW(const float* __restrict__ src, u16* __restrict__ dst, int ngroups) {
    int g = blockIdx.x * 256 + threadIdx.x;
    if (g < ngroups) {
        float v[8];
        *(float4*)v = *(const float4*)(src + (size_t)g * 8);
        *(float4*)(v + 4) = *(const float4*)(src + (size_t)g * 8 + 4);
        emit8(dst + (size_t)g * 16, v);
    }
}
// x slice of the 4 sequences at step t -> paired [4][NROWS][128]; XCD-matched: xcd = z*2+half
__global__ void k_split_xseq(const float* __restrict__ s2, const float* __restrict__ s3,
                             const float* __restrict__ s4, const float* __restrict__ s5,
                             int t, u16* __restrict__ dst) {
    int bid = blockIdx.x;                 // 2560
    int xcd = bid & 7, chunk = bid >> 3;  // chunk 0..319
    int z = xcd >> 1, half = xcd & 1;
    int g = chunk * 256 + threadIdx.x;    // 0..81919
    int row = half * 5120 + (g >> 4);
    if (row >= NROWS) return;
    int col = (g & 15) * 8;
    const float* s = (z == 0) ? s2 : (z == 1) ? s3 : (z == 2) ? s4 : s5;
    const float* p = s + (size_t)row * (TSEQ * FDIM) + t * FDIM + col;
    float v[8];
    *(float4*)v = *(const float4*)p;
    *(float4*)(v + 4) = *(const float4*)(p + 4);
    emit8(dst + (size_t)z * 2560000 + (size_t)row * 256 + (size_t)(g & 15) * 16, v);
}
// tree x slice at step t -> paired [NROWS][128]; XCD-matched: xcd ~ row/1280
__global__ void k_split_xtree(const float* __restrict__ tree, int t, u16* __restrict__ dst) {
    int bid = blockIdx.x;                 // 640
    int xcd = bid & 7, chunk = bid >> 3;  // 0..79
    int g = chunk * 256 + threadIdx.x;    // 0..20479
    int row = xcd * 1280 + (g >> 4);
    if (row >= NROWS) return;
    int col = (g & 15) * 8;
    const float* p = tree + (size_t)row * (LTREE * FDIM) + t * FDIM + col;
    float v[8];
    *(float4*)v = *(const float4*)p;
    *(float4*)(v + 4) = *(const float4*)(p + 4);
    emit8(dst + (size_t)row * 256 + (size_t)(g & 15) * 16, v);
}
// flat [NROWS][256] f32 -> paired
__global__ void k_splitNH(const float* __restrict__ src, u16* __restrict__ dst) {
    int g = blockIdx.x * 256 + threadIdx.x;  // 320000 groups
    if (g < NROWS * 32) {
        float v[8];
        *(float4*)v = *(const float4*)(src + (size_t)g * 8);
        *(float4*)(v + 4) = *(const float4*)(src + (size_t)g * 8 + 4);
        emit8(dst + (size_t)g * 16, v);
    }
}

// ---------------------------------------------------------------------------
// GRU step: wave = 128 rows (8 rf) x 16 cols/gate. 2 waves/SIMD (big VGPR).
// grid (16, 20, z). Paired operands, imm-offset loads, fully unrolled.
// ---------------------------------------------------------------------------
template <int KX>
__global__ __launch_bounds__(256, 2) void k_rnn_step(
    const u16* __restrict__ xp, long long xzs, int xld2, int xc0, int xc1,
    const u16* __restrict__ Wih, long long wz,
    const u16* __restrict__ Whh, long long wzh,
    const float* __restrict__ bihB, const float* __restrict__ bhhB,
    const u16* __restrict__ hp, long long hz,
    u16* __restrict__ op, long long ozs, int oldv2, int ocoff) {
    const int tid = threadIdx.x, lane = tid & 63, w = tid >> 6;
    const int lx = lane & 15, kl = (lane >> 4) * 8;
    int cbi, yy, z;
    xcd_swz(cbi, yy, z);
    const int cb = cbi * 16, m0 = yy * 512 + w * 128;
    int arow[8];
#pragma unroll
    for (int rf = 0; rf < 8; rf++) {
        int r = m0 + rf * 16 + lx;
        arow[rf] = (r < NROWS) ? r : NROWS - 1;
    }
    const u16* xb = xp + (size_t)z * xzs + (size_t)((z == 1) ? xc1 : xc0) * 2;
    const u16* Wihz = Wih + (size_t)z * wz;
    const u16* Whhz = Whh + (size_t)z * wzh;
    const u16* hpz = hp + (size_t)z * hz;
    const float* bih = bihB + z * 768;
    const float* bhh = bhhB + z * 768;

    const f32x4 zf = {0.f, 0.f, 0.f, 0.f};
    f32x4 aR[8], aZ[8], aNX[8], aNH[8];
#pragma unroll
    for (int rf = 0; rf < 8; rf++) { aR[rf] = zf; aZ[rf] = zf; aNX[rf] = zf; aNH[rf] = zf; }

    {   // ---- phase X: x @ Wih^T (classes r, z, nx)
        const u16* ax[8];
#pragma unroll
        for (int rf = 0; rf < 8; rf++) ax[rf] = xb + (size_t)arow[rf] * xld2 + kl * 2;
        const u16* bx0 = Wihz + (size_t)(cb + lx) * (KX * 2) + kl * 2;
        const u16* bx1 = bx0 + 256 * KX * 2;
        const u16* bx2 = bx0 + 512 * KX * 2;
#pragma unroll
        for (int kb = 0; kb < KX; kb += 32) {
            short8 axh[8], axl[8];
#pragma unroll
            for (int rf = 0; rf < 8; rf++) {
                axh[rf] = ldf(ax[rf] + kb * 2);
                axl[rf] = ldf(ax[rf] + kb * 2 + 8);
            }
            {
                short8 bh = ldf(bx0 + kb * 2), bl = ldf(bx0 + kb * 2 + 8);
#pragma unroll
                for (int rf = 0; rf < 8; rf++) MF3(axh[rf], axl[rf], bh, bl, aR[rf]);
            }
            {
                short8 bh = ldf(bx1 + kb * 2), bl = ldf(bx1 + kb * 2 + 8);
#pragma unroll
                for (int rf = 0; rf < 8; rf++) MF3(axh[rf], axl[rf], bh, bl, aZ[rf]);
            }
            {
                short8 bh = ldf(bx2 + kb * 2), bl = ldf(bx2 + kb * 2 + 8);
#pragma unroll
                for (int rf = 0; rf < 8; rf++) MF3(axh[rf], axl[rf], bh, bl, aNX[rf]);
            }
        }
    }
    {   // ---- phase H: h @ Whh^T (classes r, z, nh)
        const u16* ah[8];
#pragma unroll
        for (int rf = 0; rf < 8; rf++) ah[rf] = hpz + (size_t)arow[rf] * 512 + kl * 2;
        const u16* bh0 = Whhz + (size_t)(cb + lx) * 512 + kl * 2;
        const u16* bh1 = bh0 + 131072;
        const u16* bh2 = bh0 + 262144;
#pragma unroll
        for (int kb = 0; kb < 256; kb += 32) {
            short8 axh[8], axl[8];
#pragma unroll
            for (int rf = 0; rf < 8; rf++) {
                axh[rf] = ldf(ah[rf] + kb * 2);
                axl[rf] = ldf(ah[rf] + kb * 2 + 8);
            }
            {
                short8 bh = ldf(bh0 + kb * 2), bl = ldf(bh0 + kb * 2 + 8);
#pragma unroll
                for (int rf = 0; rf < 8; rf++) MF3(axh[rf], axl[rf], bh, bl, aR[rf]);
            }
            {
                short8 bh = ldf(bh1 + kb * 2), bl = ldf(bh1 + kb * 2 + 8);
#pragma unroll
                for (int rf = 0; rf < 8; rf++) MF3(axh[rf], axl[rf], bh, bl, aZ[rf]);
            }
            {
                short8 bh = ldf(bh2 + kb * 2), bl = ldf(bh2 + kb * 2 + 8);
#pragma unroll
                for (int rf = 0; rf < 8; rf++) MF3(axh[rf], axl[rf], bh, bl, aNH[rf]);
            }
        }
    }
    const int col = cb + lx;
    const float b_r = bih[col] + bhh[col];
    const float b_z = bih[256 + col] + bhh[256 + col];
    const float bx_n = bih[512 + col], bh_n = bhh[512 + col];
    const int cpo = ((col >> 3) << 4) + (col & 7);
    u16* ob = op + (size_t)z * ozs + (size_t)ocoff * 2;
#pragma unroll
    for (int rf = 0; rf < 8; rf++) {
#pragma unroll
        for (int rr = 0; rr < 4; rr++) {
            int row = m0 + rf * 16 + (lane >> 4) * 4 + rr;
            if (row < NROWS) {
                float rg = fsig_(aR[rf][rr] + b_r);
                float zg = fsig_(aZ[rf][rr] + b_z);
                float ng = ftanh_(aNX[rf][rr] + bx_n + rg * (aNH[rf][rr] + bh_n));
                size_t hidx = (size_t)row * 512 + cpo;
                float hold = bf2f(hpz[hidx]) + bf2f(hpz[hidx + 8]);
                float hnew = (1.f - zg) * ng + zg * hold;
                size_t oi = (size_t)row * oldv2 + cpo;
                u16 hh = f2bf(hnew);
                ob[oi] = hh;
                ob[oi + 8] = f2bf(hnew - bf2f(hh));
            }
        }
    }
}

// ---------------------------------------------------------------------------
// TreeLSTM step (chain): 8 rf, 4 classes (i,o,u,f), c f32 in-place.
// ---------------------------------------------------------------------------
__global__ __launch_bounds__(256, 2) void k_tree_step_mf(
    const u16* __restrict__ txp,
    const u16* __restrict__ Wx, const u16* __restrict__ Wh,
    const u16* __restrict__ Wfx, const u16* __restrict__ Wfh,
    const float* __restrict__ bioux, const float* __restrict__ biouh,
    const float* __restrict__ bfx, const float* __restrict__ bfh,
    const u16* __restrict__ hp, float* __restrict__ cst,
    u16* __restrict__ op, int oldv2) {
    const int tid = threadIdx.x, lane = tid & 63, w = tid >> 6;
    const int lx = lane & 15, kl = (lane >> 4) * 8;
    int cbi, yy, zz;
    xcd_swz(cbi, yy, zz);
    const int cb = cbi * 16, m0 = yy * 512 + w * 128;
    int arow[8];
#pragma unroll
    for (int rf = 0; rf < 8; rf++) {
        int r = m0 + rf * 16 + lx;
        arow[rf] = (r < NROWS) ? r : NROWS - 1;
    }
    const f32x4 zf = {0.f, 0.f, 0.f, 0.f};
    f32x4 aI[8], aO[8], aU[8], aF[8];
#pragma unroll
    for (int rf = 0; rf < 8; rf++) { aI[rf] = zf; aO[rf] = zf; aU[rf] = zf; aF[rf] = zf; }
    {
        const u16* ax[8];
#pragma unroll
        for (int rf = 0; rf < 8; rf++) ax[rf] = txp + (size_t)arow[rf] * 256 + kl * 2;
        const u16* bx0 = Wx + (size_t)(cb + lx) * 256 + kl * 2;
        const u16* bx1 = bx0 + 65536;
        const u16* bx2 = bx0 + 131072;
        const u16* bf0 = Wfx + (size_t)(cb + lx) * 256 + kl * 2;
#pragma unroll
        for (int kb = 0; kb < 128; kb += 32) {
            short8 axh[8], axl[8];
#pragma unroll
            for (int rf = 0; rf < 8; rf++) {
                axh[rf] = ldf(ax[rf] + kb * 2);
                axl[rf] = ldf(ax[rf] + kb * 2 + 8);
            }
            {
                short8 bh = ldf(bx0 + kb * 2), bl = ldf(bx0 + kb * 2 + 8);
#pragma unroll
                for (int rf = 0; rf < 8; rf++) MF3(axh[rf], axl[rf], bh, bl, aI[rf]);
            }
            {
                short8 bh = ldf(bx1 + kb * 2), bl = ldf(bx1 + kb * 2 + 8);
#pragma unroll
                for (int rf = 0; rf < 8; rf++) MF3(axh[rf], axl[rf], bh, bl, aO[rf]);
            }
            {
                short8 bh = ldf(bx2 + kb * 2), bl = ldf(bx2 + kb * 2 + 8);
#pragma unroll
                for (int rf = 0; rf < 8; rf++) MF3(axh[rf], axl[rf], bh, bl, aU[rf]);
            }
            {
                short8 bh = ldf(bf0 + kb * 2), bl = ldf(bf0 + kb * 2 + 8);
#pragma unroll
                for (int rf = 0; rf < 8; rf++) MF3(axh[rf], axl[rf], bh, bl, aF[rf]);
            }
        }
    }
    {
        const u16* ah[8];
#pragma unroll
        for (int rf = 0; rf < 8; rf++) ah[rf] = hp + (size_t)arow[rf] * 512 + kl * 2;
        const u16* bh0 = Wh + (size_t)(cb + lx) * 512 + kl * 2;
        const u16* bh1 = bh0 + 131072;
        const u16* bh2 = bh0 + 262144;
        const u16* bf0 = Wfh + (size_t)(cb + lx) * 512 + kl * 2;
#pragma unroll
        for (int kb = 0; kb < 256; kb += 32) {
            short8 axh[8], axl[8];
#pragma unroll
            for (int rf = 0; rf < 8; rf++) {
                axh[rf] = ldf(ah[rf] + kb * 2);
                axl[rf] = ldf(ah[rf] + kb * 2 + 8);
            }
            {
                short8 bh = ldf(bh0 + kb * 2), bl = ldf(bh0 + kb * 2 + 8);
#pragma unroll
                for (int rf = 0; rf < 8; rf++) MF3(axh[rf], axl[rf], bh, bl, aI[rf]);
            }
            {
                short8 bh = ldf(bh1 + kb * 2), bl = ldf(bh1 + kb * 2 + 8);
#pragma unroll
                for (int rf = 0; rf < 8; rf++) MF3(axh[rf], axl[rf], bh, bl, aO[rf]);
            }
            {
                short8 bh = ldf(bh2 + kb * 2), bl = ldf(bh2 + kb * 2 + 8);
#pragma unroll
                for (int rf = 0; rf < 8; rf++) MF3(axh[rf], axl[rf], bh, bl, aU[rf]);
            }
            {
                short8 bh = ldf(bf0 + kb * 2), bl = ldf(bf0 + kb * 2 + 8);
#pragma unroll
                for (int rf = 0; rf < 8; rf++) MF3(axh[rf], axl[rf], bh, bl, aF[rf]);
            }
        }
    }
    const int col = cb + lx;
    const float b_i = bioux[col] + biouh[col];
    const float b_o = bioux[256 + col] + biouh[256 + col];
    const float b_u = bioux[512 + col] + biouh[512 + col];
    const float b_f = bfx[col] + bfh[col];
    const int cpo = ((col >> 3) << 4) + (col & 7);
#pragma unroll
    for (int rf = 0; rf < 8; rf++) {
#pragma unroll
        for (int rr = 0; rr < 4; rr++) {
            int row = m0 + rf * 16 + (lane >> 4) * 4 + rr;
            if (row < NROWS) {
                float ig = fsig_(aI[rf][rr] + b_i);
                float og = fsig_(aO[rf][rr] + b_o);
                float ug = ftanh_(aU[rf][rr] + b_u);
                float fg = fsig_(aF[rf][rr] + b_f);
                size_t ci = (size_t)row * H + col;
                float cnew = ig * ug + fg * cst[ci];
                cst[ci] = cnew;
                float hnew = og * ftanh_(cnew);
                size_t oi = (size_t)row * oldv2 + cpo;
                u16 hh = f2bf(hnew);
                op[oi] = hh;
                op[oi + 8] = f2bf(hnew - bf2f(hh));
            }
        }
    }
}

// fv += hf @ Wc[:,off_f:+256]^T + hb @ Wc[:,off_b:+256]^T (paired, wave 64x64)
__global__ __launch_bounds__(256) void k_fv_acc_mf(
    float* __restrict__ fv, const u16* __restrict__ hq,
    const u16* __restrict__ Wc, int off_f, int off_b) {
    const int tid = threadIdx.x, lane = tid & 63, w = tid >> 6;
    const int lx = lane & 15, kl = (lane >> 4) * 8;
    int cbi, yy, zz;
    xcd_swz(cbi, yy, zz);
    const int cb = cbi * 64, m0 = yy * 256 + w * 64;
    int arow[4];
#pragma unroll
    for (int rf = 0; rf < 4; rf++) {
        int r = m0 + rf * 16 + lx;
        arow[rf] = (r < NROWS) ? r : NROWS - 1;
    }
    const f32x4 zf = {0.f, 0.f, 0.f, 0.f};
    f32x4 acc[4][4] = {{zf, zf, zf, zf}, {zf, zf, zf, zf}, {zf, zf, zf, zf}, {zf, zf, zf, zf}};
    for (int ph = 0; ph < 2; ph++) {
        const u16* aB = hq + (size_t)ph * 5120000;
        const int off = ph ? off_b : off_f;
        const u16* a0 = aB + (size_t)arow[0] * 512 + kl * 2;
        const u16* a1 = aB + (size_t)arow[1] * 512 + kl * 2;
        const u16* a2 = aB + (size_t)arow[2] * 512 + kl * 2;
        const u16* a3 = aB + (size_t)arow[3] * 512 + kl * 2;
        const u16* bp0 = Wc + (size_t)(cb + lx) * 5120 + (size_t)off * 2 + kl * 2;
        const u16* bp1 = bp0 + 16 * 5120;
        const u16* bp2 = bp0 + 32 * 5120;
        const u16* bp3 = bp0 + 48 * 5120;
#pragma unroll
        for (int kb = 0; kb < 256; kb += 32) {
            short8 axh[4], axl[4];
            axh[0] = ldf(a0 + kb * 2); axl[0] = ldf(a0 + kb * 2 + 8);
            axh[1] = ldf(a1 + kb * 2); axl[1] = ldf(a1 + kb * 2 + 8);
            axh[2] = ldf(a2 + kb * 2); axl[2] = ldf(a2 + kb * 2 + 8);
            axh[3] = ldf(a3 + kb * 2); axl[3] = ldf(a3 + kb * 2 + 8);
            {
                short8 bh = ldf(bp0 + kb * 2), bl = ldf(bp0 + kb * 2 + 8);
#pragma unroll
                for (int rf = 0; rf < 4; rf++) MF3(axh[rf], axl[rf], bh, bl, acc[rf][0]);
            }
            {
                short8 bh = ldf(bp1 + kb * 2), bl = ldf(bp1 + kb * 2 + 8);
#pragma unroll
                for (int rf = 0; rf < 4; rf++) MF3(axh[rf], axl[rf], bh, bl, acc[rf][1]);
            }
            {
                short8 bh = ldf(bp2 + kb * 2), bl = ldf(bp2 + kb * 2 + 8);
#pragma unroll
                for (int rf = 0; rf < 4; rf++) MF3(axh[rf], axl[rf], bh, bl, acc[rf][2]);
            }
            {
                short8 bh = ldf(bp3 + kb * 2), bl = ldf(bp3 + kb * 2 + 8);
#pragma unroll
                for (int rf = 0; rf < 4; rf++) MF3(axh[rf], axl[rf], bh, bl, acc[rf][3]);
            }
        }
    }
#pragma unroll
    for (int rf = 0; rf < 4; rf++) {
#pragma unroll
        for (int cf = 0; cf < 4; cf++) {
            int col = cb + cf * 16 + lx;
#pragma unroll
            for (int rr = 0; rr < 4; rr++) {
                int row = m0 + rf * 16 + (lane >> 4) * 4 + rr;
                if (row < NROWS) fv[(size_t)row * H + col] += acc[rf][cf][rr];
            }
        }
    }
}

// out = A @ W^T  (A paired [N,512u16], W paired [256][512u16])
__global__ __launch_bounds__(256) void k_gcn_gemm(
    float* __restrict__ out, const u16* __restrict__ ap_, const u16* __restrict__ W) {
    const int tid = threadIdx.x, lane = tid & 63, w = tid >> 6;
    const int lx = lane & 15, kl = (lane >> 4) * 8;
    int cbi, yy, zz;
    xcd_swz(cbi, yy, zz);
    const int cb = cbi * 64, m0 = yy * 256 + w * 64;
    int arow[4];
#pragma unroll
    for (int rf = 0; rf < 4; rf++) {
        int r = m0 + rf * 16 + lx;
        arow[rf] = (r < NROWS) ? r : NROWS - 1;
    }
    const f32x4 zf = {0.f, 0.f, 0.f, 0.f};
    f32x4 acc[4][4] = {{zf, zf, zf, zf}, {zf, zf, zf, zf}, {zf, zf, zf, zf}, {zf, zf, zf, zf}};
    const u16* a0 = ap_ + (size_t)arow[0] * 512 + kl * 2;
    const u16* a1 = ap_ + (size_t)arow[1] * 512 + kl * 2;
    const u16* a2 = ap_ + (size_t)arow[2] * 512 + kl * 2;
    const u16* a3 = ap_ + (size_t)arow[3] * 512 + kl * 2;
    const u16* bp0 = W + (size_t)(cb + lx) * 512 + kl * 2;
    const u16* bp1 = bp0 + 16 * 512;
    const u16* bp2 = bp0 + 32 * 512;
    const u16* bp3 = bp0 + 48 * 512;
#pragma unroll
    for (int kb = 0; kb < 256; kb += 32) {
        short8 axh[4], axl[4];
        axh[0] = ldf(a0 + kb * 2); axl[0] = ldf(a0 + kb * 2 + 8);
        axh[1] = ldf(a1 + kb * 2); axl[1] = ldf(a1 + kb * 2 + 8);
        axh[2] = ldf(a2 + kb * 2); axl[2] = ldf(a2 + kb * 2 + 8);
        axh[3] = ldf(a3 + kb * 2); axl[3] = ldf(a3 + kb * 2 + 8);
        {
            short8 bh = ldf(bp0 + kb * 2), bl = ldf(bp0 + kb * 2 + 8);
#pragma unroll
            for (int rf = 0; rf < 4; rf++) MF3(axh[rf], axl[rf], bh, bl, acc[rf][0]);
        }
        {
            short8 bh = ldf(bp1 + kb * 2), bl = ldf(bp1 + kb * 2 + 8);
#pragma unroll
            for (int rf = 0; rf < 4; rf++) MF3(axh[rf], axl[rf], bh, bl, acc[rf][1]);
        }
        {
            short8 bh = ldf(bp2 + kb * 2), bl = ldf(bp2 + kb * 2 + 8);
#pragma unroll
            for (int rf = 0; rf < 4; rf++) MF3(axh[rf], axl[rf], bh, bl, acc[rf][2]);
        }
        {
            short8 bh = ldf(bp3 + kb * 2), bl = ldf(bp3 + kb * 2 + 8);
#pragma unroll
            for (int rf = 0; rf < 4; rf++) MF3(axh[rf], axl[rf], bh, bl, acc[rf][3]);
        }
    }
#pragma unroll
    for (int rf = 0; rf < 4; rf++) {
#pragma unroll
        for (int cf = 0; cf < 4; cf++) {
            int col = cb + cf * 16 + lx;
#pragma unroll
            for (int rr = 0; rr < 4; rr++) {
                int row = m0 + rf * 16 + (lane >> 4) * 4 + rr;
                if (row < NROWS) out[(size_t)row * H + col] = acc[rf][cf][rr];
            }
        }
    }
}

// ---------------------------- GCN small kernels -----------------------------
__global__ void k_fv_init(float* fv, const float* __restrict__ b) {
    int idx = blockIdx.x * 256 + threadIdx.x;
    if (idx < NROWS * H) fv[idx] = b[idx & (H - 1)];
}
__global__ void k_cnt(int* __restrict__ cnt, const int* __restrict__ dst) {
    int i = blockIdx.x * 256 + threadIdx.x;
    if (i < NE) atomicAdd(&cnt[dst[i]], 1);
}
__global__ void k_scan(const int* __restrict__ cnt, int* __restrict__ rowptr) {
    __shared__ int part[256];
    int tid = threadIdx.x;
    int st = tid * 40, en = (st + 40 > NROWS) ? NROWS : st + 40;
    int s = 0;
    for (int i = st; i < en; i++) s += cnt[i];
    part[tid] = s;
    __syncthreads();
    if (tid == 0) {
        int run = 0;
        for (int i = 0; i < 256; i++) { int t = part[i]; part[i] = run; run += t; }
        rowptr[NROWS] = run;
    }
    __syncthreads();
    int run = part[tid];
    for (int i = st; i < en; i++) { rowptr[i] = run; run += cnt[i]; }
}
__global__ void k_dinv(float* __restrict__ dinv, const int* __restrict__ cnt) {
    int i = blockIdx.x * 256 + threadIdx.x;
    if (i < NROWS) dinv[i] = rsqrtf(1.0f + (float)cnt[i]);
}
__global__ void k_fill(int* __restrict__ csr, int* __restrict__ cursor,
                       const int* __restrict__ rowptr, const int* __restrict__ ei) {
    int e = blockIdx.x * 256 + threadIdx.x;
    if (e < NE) {
        int d = ei[NE + e];
        int p = atomicAdd(&cursor[d], 1);
        csr[rowptr[d] + p] = ei[e];
    }
}
// out[node] = relu(norm-agg + b); also emits paired bf16 split for the next conv
__global__ __launch_bounds__(256) void k_gather(
    float* __restrict__ out, u16* __restrict__ xcp,
    const float* __restrict__ xw, const float* __restrict__ dinv,
    const int* __restrict__ rowptr, const int* __restrict__ csr, const float* __restrict__ b) {
    int node = blockIdx.x * 4 + (threadIdx.x >> 6);
    if (node >= NROWS) return;
    int lane = threadIdx.x & 63;
    float dn = dinv[node];
    float4 acc = *(const float4*)(xw + (size_t)node * H + lane * 4);
    float dn2 = dn * dn;
    acc.x *= dn2; acc.y *= dn2; acc.z *= dn2; acc.w *= dn2;
    int e0 = rowptr[node], e1 = rowptr[node + 1];
    for (int i = e0; i < e1; i++) {
        int s = csr[i];
        float wgt = dn * dinv[s];
        const float4 v = *(const float4*)(xw + (size_t)s * H + lane * 4);
        acc.x += v.x * wgt; acc.y += v.y * wgt; acc.z += v.z * wgt; acc.w += v.w * wgt;
    }
    const float4 bv = *(const float4*)(b + lane * 4);
    float o[4];
    o[0] = fmaxf(acc.x + bv.x, 0.f);
    o[1] = fmaxf(acc.y + bv.y, 0.f);
    o[2] = fmaxf(acc.z + bv.z, 0.f);
    o[3] = fmaxf(acc.w + bv.w, 0.f);
    *(float4*)(out + (size_t)node * H + lane * 4) = *(const float4*)o;
    u16 hs[4], ls[4];
#pragma unroll
    for (int j = 0; j < 4; j++) {
        hs[j] = f2bf(o[j]);
        ls[j] = f2bf(o[j] - bf2f(hs[j]));
    }
    size_t bidx = (size_t)node * 512 + (size_t)(lane >> 1) * 16 + (lane & 1) * 4;
    *(short4*)(xcp + bidx) = *(const short4*)hs;
    *(short4*)(xcp + bidx + 8) = *(const short4*)ls;
}
__global__ void k_colmax(float* __restrict__ out, const float* __restrict__ x) {
    int j = threadIdx.x;
    float m = 0.0f;
    for (int r = blockIdx.x; r < NROWS; r += gridDim.x)
        m = fmaxf(m, x[(size_t)r * H + j]);
    atomicMax((int*)&out[j], __float_as_int(m));
}

// ---------------------------------------------------------------------------
extern "C" void kernel_launch(void* const* d_in, const int* in_sizes, int n_in,
                              void* d_out, int out_size, void* d_ws, size_t ws_size,
                              hipStream_t stream) {
    const float* tree = (const float*)d_in[0];
    const float* s2 = (const float*)d_in[1];
    const float* s3 = (const float*)d_in[2];
    const float* s4 = (const float*)d_in[3];
    const float* s5 = (const float*)d_in[4];
    const int* edge = (const int*)d_in[5];
    const float* tl_Wioux = (const float*)d_in[6];
    const float* tl_bioux = (const float*)d_in[7];
    const float* tl_Wiouh = (const float*)d_in[8];
    const float* tl_biouh = (const float*)d_in[9];
    const float* tl_Wfx = (const float*)d_in[10];
    const float* tl_bfx = (const float*)d_in[11];
    const float* tl_Wfh = (const float*)d_in[12];
    const float* tl_bfh = (const float*)d_in[13];
    const float* gru_Wih = (const float*)d_in[14];
    const float* gru_Whh = (const float*)d_in[15];
    const float* gru_bih = (const float*)d_in[16];
    const float* gru_bhh = (const float*)d_in[17];
    const float* comb_Wih = (const float*)d_in[18];
    const float* comb_Whh = (const float*)d_in[19];
    const float* comb_bih = (const float*)d_in[20];
    const float* comb_bhh = (const float*)d_in[21];
    const float* connect_W = (const float*)d_in[22];
    const float* connect_b = (const float*)d_in[23];
    const float* gcn_W = (const float*)d_in[24];
    const float* gcn_b = (const float*)d_in[25];

    char* base = (char*)d_ws;
    size_t off = 0;
    auto aus = [&](size_t nu16) { u16* p = (u16*)(base + off); off += nu16 * sizeof(u16); return p; };
    u16* tx = aus(196608);
    u16* th = aus(393216);
    u16* tfx = aus(65536);
    u16* tfh = aus(131072);
    u16* gWih = aus(786432);
    u16* gWhh = aus(1572864);
    u16* cWih = aus(786432);
    u16* cWhh = aus(786432);
    u16* cn = aus(1310720);
    u16* gc = aus(393216);
    u16* feats = aus((size_t)NROWS * 2560);   // [10000][1280] paired
    u16* hA = aus((size_t)4 * NROWS * 512);
    u16* hB = aus((size_t)4 * NROWS * 512);
    u16* SA = aus((size_t)10240000);          // 20.48 MB scratch

    const dim3 blk(256);

    hipMemsetAsync(d_out, 0, H * sizeof(float), stream);

    auto SPW = [&](const float* s, u16* d, int n) {
        k_splitW<<<(n / 8 + 255) / 256, blk, 0, stream>>>(s, d, n / 8);
    };
    SPW(tl_Wioux, tx, 98304);
    SPW(tl_Wiouh, th, 196608);
    SPW(tl_Wfx, tfx, 32768);
    SPW(tl_Wfh, tfh, 65536);
    SPW(gru_Wih, gWih, 393216);
    SPW(gru_Whh, gWhh, 786432);
    SPW(comb_Wih, cWih, 393216);
    SPW(comb_Whh, cWhh, 393216);
    SPW(connect_W, cn, 655360);
    SPW(gcn_W, gc, 196608);

    // -------- TreeLSTM (8 steps) --------
    float* cbuf = (float*)SA;
    u16* xtree = SA + 5120000;
    hipMemsetAsync(hA, 0, (size_t)NROWS * 512 * 2, stream);
    hipMemsetAsync(cbuf, 0, (size_t)NROWS * H * 4, stream);
    {
        u16 *p = hA, *q = hB;
        for (int t = 0; t < LTREE; ++t) {
            bool last = (t == LTREE - 1);
            k_split_xtree<<<640, blk, 0, stream>>>(tree, t, xtree);
            k_tree_step_mf<<<dim3(16, 20, 1), blk, 0, stream>>>(
                xtree, tx, th, tfx, tfh, tl_bioux, tl_biouh, tl_bfx, tl_bfh,
                p, cbuf, last ? feats : q, last ? 2560 : 512);
            u16* tmp = p; p = q; q = tmp;
        }
    }

    // -------- 4 GRUs (16 steps, z=4) --------
    u16* xs = SA;
    hipMemsetAsync(hA, 0, (size_t)4 * NROWS * 512 * 2, stream);
    {
        u16 *p = hA, *q = hB;
        for (int t = 0; t < TSEQ; ++t) {
            bool last = (t == TSEQ - 1);
            k_split_xseq<<<2560, blk, 0, stream>>>(s2, s3, s4, s5, t, xs);
            k_rnn_step<128><<<dim3(16, 20, 4), blk, 0, stream>>>(
                xs, 2560000LL, 256, 0, 0,
                gWih, 196608LL, gWhh, 393216LL, gru_bih, gru_bhh,
                p, (long long)NROWS * 512,
                last ? feats + 512 : q, last ? 512LL : (long long)NROWS * 512,
                last ? 2560 : 512, 0);
            u16* tmp = p; p = q; q = tmp;
        }
    }

    // -------- combine bi-GRU (5 steps, z=2) + fused connect --------
    float* fv = (float*)SA;
    hipMemsetAsync(hA, 0, (size_t)2 * NROWS * 512 * 2, stream);
    k_fv_init<<<(NROWS * H + 255) / 256, blk, 0, stream>>>(fv, connect_b);
    {
        u16 *p = hA, *q = hB;
        for (int s = 0; s < 5; ++s) {
            k_rnn_step<256><<<dim3(16, 20, 2), blk, 0, stream>>>(
                feats, 0LL, 2560, s * 256, (4 - s) * 256,
                cWih, 393216LL, cWhh, 393216LL, comb_bih, comb_bhh,
                p, (long long)NROWS * 512,
                q, (long long)NROWS * 512, 512, 0);
            k_fv_acc_mf<<<dim3(4, 40, 1), blk, 0, stream>>>(
                fv, q, cn, s * 512, (4 - s) * 512 + 256);
            u16* tmp = p; p = q; q = tmp;
        }
    }

    // -------- CSR build --------
    int* cnt = (int*)(hB + 6000000);
    int* rowptr = cnt + 10016;
    int* cursor = rowptr + 10016;
    int* csr = cursor + 10016;
    float* dinv = (float*)(csr + NE);
    hipMemsetAsync(cnt, 0, NROWS * sizeof(int), stream);
    hipMemsetAsync(cursor, 0, NROWS * sizeof(int), stream);
    k_cnt<<<(NE + 255) / 256, blk, 0, stream>>>(cnt, edge + NE);
    k_scan<<<1, blk, 0, stream>>>(cnt, rowptr);
    k_dinv<<<(NROWS + 255) / 256, blk, 0, stream>>>(dinv, cnt);
    k_fill<<<(NE + 255) / 256, blk, 0, stream>>>(csr, cursor, rowptr, edge);

    // -------- 4 conv applications (last two share W2,b2) --------
    {
        u16* xc = hB;
        float* xw = (float*)(SA + 5120000);
        float* xb = (float*)hA;
        float* cur = fv;
        float* nxt = xb;
        k_splitNH<<<1250, blk, 0, stream>>>(fv, xc);
        for (int i = 0; i < 4; ++i) {
            int wi = (i < 3) ? i : 2;
            k_gcn_gemm<<<dim3(4, 40, 1), blk, 0, stream>>>(xw, xc, gc + (size_t)wi * 131072);
            k_gather<<<(NROWS + 3) / 4, blk, 0, stream>>>(nxt, xc, xw, dinv, rowptr, csr,
                                                          gcn_b + wi * H);
            float* tmp = cur; cur = nxt; nxt = tmp;
        }
        k_colmax<<<256, blk, 0, stream>>>((float*)d_out, cur);
    }
}